// Round 1
// baseline (709.444 us; speedup 1.0000x reference)
//
#include <hip/hip_runtime.h>

#define T_SEQ 256
#define N_DIM 2048
#define D_DIM 128
#define B_BATCH 8

// ---------------- gather: Vp[r,:] = token_emb[tokens[r]] ----------------
__global__ __launch_bounds__(128) void k_gather(const float* __restrict__ emb,
                                                const int* __restrict__ toks,
                                                float* __restrict__ Vp) {
  int r = blockIdx.x;
  int d = threadIdx.x;
  int tok = toks[r];
  Vp[(long)r * D_DIM + d] = emb[(long)tok * D_DIM + d];
}

// ---------------- generic C[M,N] = A[M,K] @ B[N,K]^T (row-major) --------
// FUSE=1: C = relu(C) * relu(Xr)   (Xr same shape/stride as C)
template <int FUSE>
__global__ __launch_bounds__(256) void k_gemm_abT(
    const float* __restrict__ A, const float* __restrict__ Bm, float* __restrict__ C,
    int M, int N, int K, long sA, long sB, long sC, const float* __restrict__ Xr) {
  constexpr int BM = 64, BN = 64, BK = 16;
  A += (long)blockIdx.z * sA;
  Bm += (long)blockIdx.z * sB;
  C += (long)blockIdx.z * sC;
  const float* Xp = Xr ? Xr + (long)blockIdx.z * sC : nullptr;

  __shared__ float As[BK][BM + 4];
  __shared__ float Bs[BK][BN + 4];
  int tid = threadIdx.x;
  int tx = tid & 15, ty = tid >> 4;
  int row0 = blockIdx.y * BM, col0 = blockIdx.x * BN;
  float acc[4][4] = {};

  for (int k0 = 0; k0 < K; k0 += BK) {
#pragma unroll
    for (int i = 0; i < 4; i++) {
      int idx = tid + i * 256;
      int m = idx >> 4;  // 0..63
      int k = idx & 15;  // 0..15
      As[k][m] = A[(long)(row0 + m) * K + k0 + k];
      Bs[k][m] = Bm[(long)(col0 + m) * K + k0 + k];
    }
    __syncthreads();
#pragma unroll
    for (int k = 0; k < BK; k++) {
      float a[4], b[4];
#pragma unroll
      for (int i = 0; i < 4; i++) a[i] = As[k][ty * 4 + i];
#pragma unroll
      for (int j = 0; j < 4; j++) b[j] = Bs[k][tx * 4 + j];
#pragma unroll
      for (int i = 0; i < 4; i++)
#pragma unroll
        for (int j = 0; j < 4; j++) acc[i][j] += a[i] * b[j];
    }
    __syncthreads();
  }
#pragma unroll
  for (int i = 0; i < 4; i++) {
    long r = row0 + ty * 4 + i;
    long c = col0 + tx * 4;
    long off = r * (long)N + c;
    float4 v = make_float4(acc[i][0], acc[i][1], acc[i][2], acc[i][3]);
    if (FUSE) {
      float4 xv = *(const float4*)(Xp + off);
      v.x = fmaxf(v.x, 0.f) * fmaxf(xv.x, 0.f);
      v.y = fmaxf(v.y, 0.f) * fmaxf(xv.y, 0.f);
      v.z = fmaxf(v.z, 0.f) * fmaxf(xv.z, 0.f);
      v.w = fmaxf(v.w, 0.f) * fmaxf(xv.w, 0.f);
    }
    *(float4*)(C + off) = v;
  }
}

// ---------------- sequential x-scan: one wave per batch -----------------
// x_t = thresh(normalize(0.97*x_{t-1} + P_t));  writes dense X[b,t,:]
__global__ __launch_bounds__(64) void k_scan(const float* __restrict__ P,
                                             float* __restrict__ X) {
  int b = blockIdx.x;
  int lane = threadIdx.x;
  float x[32];
#pragma unroll
  for (int j = 0; j < 32; j++) x[j] = 0.f;
  const float4* Pv = (const float4*)(P + (long)b * T_SEQ * N_DIM);
  float4* Xv = (float4*)(X + (long)b * T_SEQ * N_DIM);
  for (int t = 0; t < T_SEQ; t++) {
    long rowBase = (long)t * (N_DIM / 4) + lane * 8;
    float z[32];
#pragma unroll
    for (int q = 0; q < 8; q++) {
      float4 p = Pv[rowBase + q];
      z[q * 4 + 0] = 0.97f * x[q * 4 + 0] + p.x;
      z[q * 4 + 1] = 0.97f * x[q * 4 + 1] + p.y;
      z[q * 4 + 2] = 0.97f * x[q * 4 + 2] + p.z;
      z[q * 4 + 3] = 0.97f * x[q * 4 + 3] + p.w;
    }
    float s1 = 0.f, mx = -3.4e38f;
#pragma unroll
    for (int j = 0; j < 32; j++) {
      s1 += fabsf(z[j]);
      mx = fmaxf(mx, z[j]);
    }
#pragma unroll
    for (int off = 32; off >= 1; off >>= 1) {
      s1 += __shfl_xor(s1, off);
      mx = fmaxf(mx, __shfl_xor(mx, off));
    }
    float inv = 1.f / (s1 + 1e-6f);
    float thr = 0.02f * mx;  // compare in un-normalized space (scale-invariant)
#pragma unroll
    for (int j = 0; j < 32; j++) x[j] = (z[j] > thr) ? z[j] * inv : 0.f;
#pragma unroll
    for (int q = 0; q < 8; q++)
      Xv[rowBase + q] = make_float4(x[q * 4 + 0], x[q * 4 + 1], x[q * 4 + 2], x[q * 4 + 3]);
  }
}

// ------ a_star[b,t,d] = sum_{s<t} 0.97^(t-s) * S[b,t,s] * Vp[b,s,d] -----
__global__ __launch_bounds__(128) void k_astar(const float* __restrict__ S,
                                               const float* __restrict__ Vp,
                                               float* __restrict__ A) {
  int bx = blockIdx.x;
  int b = bx >> 8, t = bx & 255;
  int d = threadIdx.x;
  const float* Sb = S + ((long)b * T_SEQ + t) * T_SEQ;
  const float* Vb = Vp + (long)b * T_SEQ * D_DIM;
  float acc = 0.f;
  float w = 1.f;
  for (int s = t - 1; s >= 0; s--) {
    w *= 0.97f;
    acc += w * Sb[s] * Vb[(long)s * D_DIM + d];
  }
  A[((long)b * T_SEQ + t) * D_DIM + d] = acc;
}

// ------------- row layernorm over D=128 (torch ddof=1 semantics) --------
__global__ __launch_bounds__(64) void k_ln(const float* __restrict__ In,
                                           float* __restrict__ Out) {
  long base = (long)blockIdx.x * D_DIM;
  int lane = threadIdx.x;
  float a = In[base + lane];
  float b = In[base + lane + 64];
  float s = a + b;
#pragma unroll
  for (int off = 32; off >= 1; off >>= 1) s += __shfl_xor(s, off);
  float m = s * (1.f / 128.f);
  float da = a - m, db = b - m;
  float v = da * da + db * db;
#pragma unroll
  for (int off = 32; off >= 1; off >>= 1) v += __shfl_xor(v, off);
  float sd = sqrtf(v * (1.f / 127.f));
  float invs = 1.f / (sd + 1e-6f);
  Out[base + lane] = da * invs;
  Out[base + lane + 64] = db * invs;
}

extern "C" void kernel_launch(void* const* d_in, const int* in_sizes, int n_in,
                              void* d_out, int out_size, void* d_ws, size_t ws_size,
                              hipStream_t stream) {
  const float* E = (const float*)d_in[0];     // [128, 2048]
  const float* Dx = (const float*)d_in[1];    // [2048, 128]
  const float* Dy = (const float*)d_in[2];    // [2048, 128]
  const float* emb = (const float*)d_in[3];   // [131072, 128]
  const int* toks = (const int*)d_in[4];      // [8, 256]
  float* out = (float*)d_out;                 // [8, 256, 128]

  char* ws = (char*)d_ws;
  const size_t MB = 1u << 20;
  float* Vp = (float*)(ws + 0 * MB);    // 1 MB   [2048,128]
  float* P = (float*)(ws + 1 * MB);     // 16 MB  [2048,2048]
  float* X = (float*)(ws + 17 * MB);    // 16 MB  [2048,2048]
  float* S = (float*)(ws + 33 * MB);    // 2 MB   [8,256,256]
  float* A = (float*)(ws + 35 * MB);    // 1 MB   [2048,128]
  float* LnA = (float*)(ws + 36 * MB);  // 1 MB
  float* U = (float*)(ws + 37 * MB);    // 1 MB
  float* Yt = P;                        // reuse P (dead after scan)

  const int R = B_BATCH * T_SEQ;  // 2048

  k_gather<<<R, D_DIM, 0, stream>>>(emb, toks, Vp);
  // P = Vp @ Dx^T : [2048,128]x[2048,128]^T -> [2048,2048]
  k_gemm_abT<0><<<dim3(N_DIM / 64, R / 64, 1), 256, 0, stream>>>(
      Vp, Dx, P, R, N_DIM, D_DIM, 0, 0, 0, nullptr);
  // sequential x-scan, independent per batch
  k_scan<<<B_BATCH, 64, 0, stream>>>(P, X);
  // S = X @ X^T per batch: [256,2048]x[256,2048]^T -> [256,256]
  k_gemm_abT<0><<<dim3(T_SEQ / 64, T_SEQ / 64, B_BATCH), 256, 0, stream>>>(
      X, X, S, T_SEQ, T_SEQ, N_DIM,
      (long)T_SEQ * N_DIM, (long)T_SEQ * N_DIM, (long)T_SEQ * T_SEQ, nullptr);
  // a_star = (decay-masked S) @ Vp
  k_astar<<<R, D_DIM, 0, stream>>>(S, Vp, A);
  k_ln<<<R, 64, 0, stream>>>(A, LnA);
  // Yt = relu(LnA @ Dy^T) * relu(X)
  k_gemm_abT<1><<<dim3(N_DIM / 64, R / 64, 1), 256, 0, stream>>>(
      LnA, Dy, Yt, R, N_DIM, D_DIM, 0, 0, 0, X);
  // U = Yt @ E^T : [2048,2048]x[128,2048]^T -> [2048,128]
  k_gemm_abT<0><<<dim3(D_DIM / 64, R / 64, 1), 256, 0, stream>>>(
      Yt, E, U, R, D_DIM, N_DIM, 0, 0, 0, nullptr);
  k_ln<<<R, 64, 0, stream>>>(U, out);
}

// Round 2
// 658.723 us; speedup vs baseline: 1.0770x; 1.0770x over previous
//
#include <hip/hip_runtime.h>

#define T_SEQ 256
#define N_DIM 2048
#define D_DIM 128
#define B_BATCH 8

// ---------------- gather: Vp[r,:] = token_emb[tokens[r]] ----------------
__global__ __launch_bounds__(128) void k_gather(const float* __restrict__ emb,
                                                const int* __restrict__ toks,
                                                float* __restrict__ Vp) {
  int r = blockIdx.x;
  int d = threadIdx.x;
  int tok = toks[r];
  Vp[(long)r * D_DIM + d] = emb[(long)tok * D_DIM + d];
}

// ---------------- generic C[M,N] = A[M,K] @ B[N,K]^T (row-major) --------
// FUSE=1: C = relu(C) * relu(Xr)   (Xr same shape/stride as C)
template <int FUSE>
__global__ __launch_bounds__(256) void k_gemm_abT(
    const float* __restrict__ A, const float* __restrict__ Bm, float* __restrict__ C,
    int M, int N, int K, long sA, long sB, long sC, const float* __restrict__ Xr) {
  constexpr int BM = 64, BN = 64, BK = 16;
  A += (long)blockIdx.z * sA;
  Bm += (long)blockIdx.z * sB;
  C += (long)blockIdx.z * sC;
  const float* Xp = Xr ? Xr + (long)blockIdx.z * sC : nullptr;

  __shared__ float As[BK][BM + 4];
  __shared__ float Bs[BK][BN + 4];
  int tid = threadIdx.x;
  int tx = tid & 15, ty = tid >> 4;
  int row0 = blockIdx.y * BM, col0 = blockIdx.x * BN;
  float acc[4][4] = {};

  for (int k0 = 0; k0 < K; k0 += BK) {
#pragma unroll
    for (int i = 0; i < 4; i++) {
      int idx = tid + i * 256;
      int m = idx >> 4;  // 0..63
      int k = idx & 15;  // 0..15
      As[k][m] = A[(long)(row0 + m) * K + k0 + k];
      Bs[k][m] = Bm[(long)(col0 + m) * K + k0 + k];
    }
    __syncthreads();
#pragma unroll
    for (int k = 0; k < BK; k++) {
      float a[4], b[4];
#pragma unroll
      for (int i = 0; i < 4; i++) a[i] = As[k][ty * 4 + i];
#pragma unroll
      for (int j = 0; j < 4; j++) b[j] = Bs[k][tx * 4 + j];
#pragma unroll
      for (int i = 0; i < 4; i++)
#pragma unroll
        for (int j = 0; j < 4; j++) acc[i][j] += a[i] * b[j];
    }
    __syncthreads();
  }
#pragma unroll
  for (int i = 0; i < 4; i++) {
    long r = row0 + ty * 4 + i;
    long c = col0 + tx * 4;
    long off = r * (long)N + c;
    float4 v = make_float4(acc[i][0], acc[i][1], acc[i][2], acc[i][3]);
    if (FUSE) {
      float4 xv = *(const float4*)(Xp + off);
      v.x = fmaxf(v.x, 0.f) * fmaxf(xv.x, 0.f);
      v.y = fmaxf(v.y, 0.f) * fmaxf(xv.y, 0.f);
      v.z = fmaxf(v.z, 0.f) * fmaxf(xv.z, 0.f);
      v.w = fmaxf(v.w, 0.f) * fmaxf(xv.w, 0.f);
    }
    *(float4*)(C + off) = v;
  }
}

// ---------------- sequential x-scan: one wave per batch -----------------
// x_t = thresh(normalize(0.97*x_{t-1} + P_t));  writes dense X[b,t,:]
// Register-double-buffered: loads for row t+1 issue before step t's compute,
// so the global-load round trip hides under the ~500cy of step-t work.
__global__ __launch_bounds__(64) void k_scan(const float* __restrict__ P,
                                             float* __restrict__ X) {
  int b = blockIdx.x;
  int lane = threadIdx.x;
  const float4* Pv = (const float4*)(P + (long)b * T_SEQ * N_DIM);
  float4* Xv = (float4*)(X + (long)b * T_SEQ * N_DIM);
  const int ROWQ = N_DIM / 4;  // 512 float4 per row

  float x[32];
#pragma unroll
  for (int j = 0; j < 32; j++) x[j] = 0.f;

  auto step = [&](const float4 (&buf)[8], int t) {
    float z[32];
#pragma unroll
    for (int q = 0; q < 8; q++) {
      z[q * 4 + 0] = 0.97f * x[q * 4 + 0] + buf[q].x;
      z[q * 4 + 1] = 0.97f * x[q * 4 + 1] + buf[q].y;
      z[q * 4 + 2] = 0.97f * x[q * 4 + 2] + buf[q].z;
      z[q * 4 + 3] = 0.97f * x[q * 4 + 3] + buf[q].w;
    }
    // per-lane tree reduce (sum|z|, max z) for ILP
    float s1 = 0.f, mx = z[0];
#pragma unroll
    for (int j = 0; j < 32; j++) s1 += fabsf(z[j]);
#pragma unroll
    for (int j = 1; j < 32; j++) mx = fmaxf(mx, z[j]);
#pragma unroll
    for (int off = 32; off >= 1; off >>= 1) {
      s1 += __shfl_xor(s1, off);
      mx = fmaxf(mx, __shfl_xor(mx, off));
    }
    float inv = 1.f / (s1 + 1e-6f);
    float thr = 0.02f * mx;  // threshold in un-normalized space (scale-invariant)
#pragma unroll
    for (int j = 0; j < 32; j++) x[j] = (z[j] > thr) ? z[j] * inv : 0.f;
    long rowBase = (long)t * ROWQ + lane * 8;
#pragma unroll
    for (int q = 0; q < 8; q++)
      Xv[rowBase + q] = make_float4(x[q * 4 + 0], x[q * 4 + 1], x[q * 4 + 2], x[q * 4 + 3]);
  };

  float4 bA[8], bB[8];
  long l8 = (long)lane * 8;
#pragma unroll
  for (int q = 0; q < 8; q++) bA[q] = Pv[l8 + q];

  for (int t = 0; t < T_SEQ; t += 2) {
    long nb1 = (long)(t + 1) * ROWQ + l8;
#pragma unroll
    for (int q = 0; q < 8; q++) bB[q] = Pv[nb1 + q];  // prefetch t+1
    step(bA, t);
    if (t + 2 < T_SEQ) {
      long nb2 = (long)(t + 2) * ROWQ + l8;
#pragma unroll
      for (int q = 0; q < 8; q++) bA[q] = Pv[nb2 + q];  // prefetch t+2
    }
    step(bB, t + 1);
  }
}

// ------ a_star[b,t,d] = sum_{s<t} 0.97^(t-s) * S[b,t,s] * Vp[b,s,d] -----
__global__ __launch_bounds__(128) void k_astar(const float* __restrict__ S,
                                               const float* __restrict__ Vp,
                                               float* __restrict__ A) {
  int bx = blockIdx.x;
  int b = bx >> 8, t = bx & 255;
  int d = threadIdx.x;
  const float* Sb = S + ((long)b * T_SEQ + t) * T_SEQ;
  const float* Vb = Vp + (long)b * T_SEQ * D_DIM;
  float acc = 0.f;
  float w = 1.f;
  for (int s = t - 1; s >= 0; s--) {
    w *= 0.97f;
    acc += w * Sb[s] * Vb[(long)s * D_DIM + d];
  }
  A[((long)b * T_SEQ + t) * D_DIM + d] = acc;
}

// ------------- row layernorm over D=128 (torch ddof=1 semantics) --------
__global__ __launch_bounds__(64) void k_ln(const float* __restrict__ In,
                                           float* __restrict__ Out) {
  long base = (long)blockIdx.x * D_DIM;
  int lane = threadIdx.x;
  float a = In[base + lane];
  float b = In[base + lane + 64];
  float s = a + b;
#pragma unroll
  for (int off = 32; off >= 1; off >>= 1) s += __shfl_xor(s, off);
  float m = s * (1.f / 128.f);
  float da = a - m, db = b - m;
  float v = da * da + db * db;
#pragma unroll
  for (int off = 32; off >= 1; off >>= 1) v += __shfl_xor(v, off);
  float sd = sqrtf(v * (1.f / 127.f));
  float invs = 1.f / (sd + 1e-6f);
  Out[base + lane] = da * invs;
  Out[base + lane + 64] = db * invs;
}

extern "C" void kernel_launch(void* const* d_in, const int* in_sizes, int n_in,
                              void* d_out, int out_size, void* d_ws, size_t ws_size,
                              hipStream_t stream) {
  const float* E = (const float*)d_in[0];     // [128, 2048]
  const float* Dx = (const float*)d_in[1];    // [2048, 128]
  const float* Dy = (const float*)d_in[2];    // [2048, 128]
  const float* emb = (const float*)d_in[3];   // [131072, 128]
  const int* toks = (const int*)d_in[4];      // [8, 256]
  float* out = (float*)d_out;                 // [8, 256, 128]

  char* ws = (char*)d_ws;
  const size_t MB = 1u << 20;
  float* Vp = (float*)(ws + 0 * MB);    // 1 MB   [2048,128]
  float* P = (float*)(ws + 1 * MB);     // 16 MB  [2048,2048]
  float* X = (float*)(ws + 17 * MB);    // 16 MB  [2048,2048]
  float* S = (float*)(ws + 33 * MB);    // 2 MB   [8,256,256]
  float* A = (float*)(ws + 35 * MB);    // 1 MB   [2048,128]
  float* LnA = (float*)(ws + 36 * MB);  // 1 MB
  float* U = (float*)(ws + 37 * MB);    // 1 MB
  float* Yt = P;                        // reuse P (dead after scan)

  const int R = B_BATCH * T_SEQ;  // 2048

  k_gather<<<R, D_DIM, 0, stream>>>(emb, toks, Vp);
  // P = Vp @ Dx^T : [2048,128]x[2048,128]^T -> [2048,2048]
  k_gemm_abT<0><<<dim3(N_DIM / 64, R / 64, 1), 256, 0, stream>>>(
      Vp, Dx, P, R, N_DIM, D_DIM, 0, 0, 0, nullptr);
  // sequential x-scan, independent per batch
  k_scan<<<B_BATCH, 64, 0, stream>>>(P, X);
  // S = X @ X^T per batch: [256,2048]x[256,2048]^T -> [256,256]
  k_gemm_abT<0><<<dim3(T_SEQ / 64, T_SEQ / 64, B_BATCH), 256, 0, stream>>>(
      X, X, S, T_SEQ, T_SEQ, N_DIM,
      (long)T_SEQ * N_DIM, (long)T_SEQ * N_DIM, (long)T_SEQ * T_SEQ, nullptr);
  // a_star = (decay-masked S) @ Vp
  k_astar<<<R, D_DIM, 0, stream>>>(S, Vp, A);
  k_ln<<<R, 64, 0, stream>>>(A, LnA);
  // Yt = relu(LnA @ Dy^T) * relu(X)
  k_gemm_abT<1><<<dim3(N_DIM / 64, R / 64, 1), 256, 0, stream>>>(
      LnA, Dy, Yt, R, N_DIM, D_DIM, 0, 0, 0, X);
  // U = Yt @ E^T : [2048,2048]x[128,2048]^T -> [2048,128]
  k_gemm_abT<0><<<dim3(D_DIM / 64, R / 64, 1), 256, 0, stream>>>(
      Yt, E, U, R, D_DIM, N_DIM, 0, 0, 0, nullptr);
  k_ln<<<R, 64, 0, stream>>>(U, out);
}

// Round 3
// 639.605 us; speedup vs baseline: 1.1092x; 1.0299x over previous
//
#include <hip/hip_runtime.h>

#define T_SEQ 256
#define N_DIM 2048
#define D_DIM 128
#define B_BATCH 8

// ---------------- gather: Vp[r,:] = token_emb[tokens[r]] ----------------
__global__ __launch_bounds__(128) void k_gather(const float* __restrict__ emb,
                                                const int* __restrict__ toks,
                                                float* __restrict__ Vp) {
  int r = blockIdx.x;
  int d = threadIdx.x;
  int tok = toks[r];
  Vp[(long)r * D_DIM + d] = emb[(long)tok * D_DIM + d];
}

// ---------------- generic C[M,N] = A[M,K] @ B[N,K]^T (row-major) --------
// FUSE=1: C = relu(C) * relu(Xr)   (Xr same shape/stride as C)
template <int FUSE>
__global__ __launch_bounds__(256) void k_gemm_abT(
    const float* __restrict__ A, const float* __restrict__ Bm, float* __restrict__ C,
    int M, int N, int K, long sA, long sB, long sC, const float* __restrict__ Xr) {
  constexpr int BM = 64, BN = 64, BK = 16;
  A += (long)blockIdx.z * sA;
  Bm += (long)blockIdx.z * sB;
  C += (long)blockIdx.z * sC;
  const float* Xp = Xr ? Xr + (long)blockIdx.z * sC : nullptr;

  __shared__ float As[BK][BM + 4];
  __shared__ float Bs[BK][BN + 4];
  int tid = threadIdx.x;
  int tx = tid & 15, ty = tid >> 4;
  int row0 = blockIdx.y * BM, col0 = blockIdx.x * BN;
  float acc[4][4] = {};

  for (int k0 = 0; k0 < K; k0 += BK) {
#pragma unroll
    for (int i = 0; i < 4; i++) {
      int idx = tid + i * 256;
      int m = idx >> 4;  // 0..63
      int k = idx & 15;  // 0..15
      As[k][m] = A[(long)(row0 + m) * K + k0 + k];
      Bs[k][m] = Bm[(long)(col0 + m) * K + k0 + k];
    }
    __syncthreads();
#pragma unroll
    for (int k = 0; k < BK; k++) {
      float a[4], b[4];
#pragma unroll
      for (int i = 0; i < 4; i++) a[i] = As[k][ty * 4 + i];
#pragma unroll
      for (int j = 0; j < 4; j++) b[j] = Bs[k][tx * 4 + j];
#pragma unroll
      for (int i = 0; i < 4; i++)
#pragma unroll
        for (int j = 0; j < 4; j++) acc[i][j] += a[i] * b[j];
    }
    __syncthreads();
  }
#pragma unroll
  for (int i = 0; i < 4; i++) {
    long r = row0 + ty * 4 + i;
    long c = col0 + tx * 4;
    long off = r * (long)N + c;
    float4 v = make_float4(acc[i][0], acc[i][1], acc[i][2], acc[i][3]);
    if (FUSE) {
      float4 xv = *(const float4*)(Xp + off);
      v.x = fmaxf(v.x, 0.f) * fmaxf(xv.x, 0.f);
      v.y = fmaxf(v.y, 0.f) * fmaxf(xv.y, 0.f);
      v.z = fmaxf(v.z, 0.f) * fmaxf(xv.z, 0.f);
      v.w = fmaxf(v.w, 0.f) * fmaxf(xv.w, 0.f);
    }
    *(float4*)(C + off) = v;
  }
}

// --------------- DPP wave-64 reduction helpers (VALU, no LDS) -----------
// row_shr:1/2/4/8 then row_bcast:15, row_bcast:31 -> lane 63 holds result.
// bound_ctrl=true zero-fills lanes with no source; harmless for sum, and
// never on the lane-63 reduce path for max.
template <int CTRL>
__device__ __forceinline__ float dpp_mov(float v) {
  return __int_as_float(
      __builtin_amdgcn_update_dpp(0, __float_as_int(v), CTRL, 0xF, 0xF, true));
}

__device__ __forceinline__ void wave_reduce_sum_max(float s, float m,
                                                    float& out_s, float& out_m) {
  s += dpp_mov<0x111>(s);  m = fmaxf(m, dpp_mov<0x111>(m));  // row_shr:1
  s += dpp_mov<0x112>(s);  m = fmaxf(m, dpp_mov<0x112>(m));  // row_shr:2
  s += dpp_mov<0x114>(s);  m = fmaxf(m, dpp_mov<0x114>(m));  // row_shr:4
  s += dpp_mov<0x118>(s);  m = fmaxf(m, dpp_mov<0x118>(m));  // row_shr:8
  s += dpp_mov<0x142>(s);  m = fmaxf(m, dpp_mov<0x142>(m));  // row_bcast:15
  s += dpp_mov<0x143>(s);  m = fmaxf(m, dpp_mov<0x143>(m));  // row_bcast:31
  out_s = __int_as_float(__builtin_amdgcn_readlane(__float_as_int(s), 63));
  out_m = __int_as_float(__builtin_amdgcn_readlane(__float_as_int(m), 63));
}

// ---------------- sequential x-scan: one wave per batch -----------------
// x_t = thresh(normalize(0.97*x_{t-1} + P_t));  writes dense X[b,t,:]
// Register-double-buffered loads + DPP reductions (no LDS round trips).
__global__ __launch_bounds__(64) void k_scan(const float* __restrict__ P,
                                             float* __restrict__ X) {
  int b = blockIdx.x;
  int lane = threadIdx.x;
  const float4* Pv = (const float4*)(P + (long)b * T_SEQ * N_DIM);
  float4* Xv = (float4*)(X + (long)b * T_SEQ * N_DIM);
  const int ROWQ = N_DIM / 4;  // 512 float4 per row

  float x[32];
#pragma unroll
  for (int j = 0; j < 32; j++) x[j] = 0.f;

  auto step = [&](const float4 (&buf)[8], int t) {
    float z[32];
#pragma unroll
    for (int q = 0; q < 8; q++) {
      z[q * 4 + 0] = 0.97f * x[q * 4 + 0] + buf[q].x;
      z[q * 4 + 1] = 0.97f * x[q * 4 + 1] + buf[q].y;
      z[q * 4 + 2] = 0.97f * x[q * 4 + 2] + buf[q].z;
      z[q * 4 + 3] = 0.97f * x[q * 4 + 3] + buf[q].w;
    }
    // per-lane pairwise trees (depth 5) for ILP
    float sa[16], ma[16];
#pragma unroll
    for (int j = 0; j < 16; j++) {
      sa[j] = fabsf(z[j]) + fabsf(z[j + 16]);
      ma[j] = fmaxf(z[j], z[j + 16]);
    }
#pragma unroll
    for (int w = 8; w >= 1; w >>= 1)
#pragma unroll
      for (int j = 0; j < w; j++) {
        sa[j] += sa[j + w];
        ma[j] = fmaxf(ma[j], ma[j + w]);
      }
    float s1, mx;
    wave_reduce_sum_max(sa[0], ma[0], s1, mx);
    float inv = 1.f / (s1 + 1e-6f);
    float thr = 0.02f * mx;  // threshold in un-normalized space (scale-invariant)
#pragma unroll
    for (int j = 0; j < 32; j++) x[j] = (z[j] > thr) ? z[j] * inv : 0.f;
    long rowBase = (long)t * ROWQ + lane * 8;
#pragma unroll
    for (int q = 0; q < 8; q++)
      Xv[rowBase + q] = make_float4(x[q * 4 + 0], x[q * 4 + 1], x[q * 4 + 2], x[q * 4 + 3]);
  };

  float4 bA[8], bB[8];
  long l8 = (long)lane * 8;
#pragma unroll
  for (int q = 0; q < 8; q++) bA[q] = Pv[l8 + q];

  for (int t = 0; t < T_SEQ; t += 2) {
    long nb1 = (long)(t + 1) * ROWQ + l8;
#pragma unroll
    for (int q = 0; q < 8; q++) bB[q] = Pv[nb1 + q];  // prefetch t+1
    step(bA, t);
    if (t + 2 < T_SEQ) {
      long nb2 = (long)(t + 2) * ROWQ + l8;
#pragma unroll
      for (int q = 0; q < 8; q++) bA[q] = Pv[nb2 + q];  // prefetch t+2
    }
    step(bB, t + 1);
  }
}

// ------ a_star[b,t,d] = sum_{s<t} 0.97^(t-s) * S[b,t,s] * Vp[b,s,d] -----
__global__ __launch_bounds__(128) void k_astar(const float* __restrict__ S,
                                               const float* __restrict__ Vp,
                                               float* __restrict__ A) {
  int bx = blockIdx.x;
  int b = bx >> 8, t = bx & 255;
  int d = threadIdx.x;
  const float* Sb = S + ((long)b * T_SEQ + t) * T_SEQ;
  const float* Vb = Vp + (long)b * T_SEQ * D_DIM;
  float acc = 0.f;
  float w = 1.f;
  for (int s = t - 1; s >= 0; s--) {
    w *= 0.97f;
    acc += w * Sb[s] * Vb[(long)s * D_DIM + d];
  }
  A[((long)b * T_SEQ + t) * D_DIM + d] = acc;
}

// ------------- row layernorm over D=128 (torch ddof=1 semantics) --------
__global__ __launch_bounds__(64) void k_ln(const float* __restrict__ In,
                                           float* __restrict__ Out) {
  long base = (long)blockIdx.x * D_DIM;
  int lane = threadIdx.x;
  float a = In[base + lane];
  float b = In[base + lane + 64];
  float s = a + b;
#pragma unroll
  for (int off = 32; off >= 1; off >>= 1) s += __shfl_xor(s, off);
  float m = s * (1.f / 128.f);
  float da = a - m, db = b - m;
  float v = da * da + db * db;
#pragma unroll
  for (int off = 32; off >= 1; off >>= 1) v += __shfl_xor(v, off);
  float sd = sqrtf(v * (1.f / 127.f));
  float invs = 1.f / (sd + 1e-6f);
  Out[base + lane] = da * invs;
  Out[base + lane + 64] = db * invs;
}

extern "C" void kernel_launch(void* const* d_in, const int* in_sizes, int n_in,
                              void* d_out, int out_size, void* d_ws, size_t ws_size,
                              hipStream_t stream) {
  const float* E = (const float*)d_in[0];     // [128, 2048]
  const float* Dx = (const float*)d_in[1];    // [2048, 128]
  const float* Dy = (const float*)d_in[2];    // [2048, 128]
  const float* emb = (const float*)d_in[3];   // [131072, 128]
  const int* toks = (const int*)d_in[4];      // [8, 256]
  float* out = (float*)d_out;                 // [8, 256, 128]

  char* ws = (char*)d_ws;
  const size_t MB = 1u << 20;
  float* Vp = (float*)(ws + 0 * MB);    // 1 MB   [2048,128]
  float* P = (float*)(ws + 1 * MB);     // 16 MB  [2048,2048]
  float* X = (float*)(ws + 17 * MB);    // 16 MB  [2048,2048]
  float* S = (float*)(ws + 33 * MB);    // 2 MB   [8,256,256]
  float* A = (float*)(ws + 35 * MB);    // 1 MB   [2048,128]
  float* LnA = (float*)(ws + 36 * MB);  // 1 MB
  float* U = (float*)(ws + 37 * MB);    // 1 MB
  float* Yt = P;                        // reuse P (dead after scan)

  const int R = B_BATCH * T_SEQ;  // 2048

  k_gather<<<R, D_DIM, 0, stream>>>(emb, toks, Vp);
  // P = Vp @ Dx^T : [2048,128]x[2048,128]^T -> [2048,2048]
  k_gemm_abT<0><<<dim3(N_DIM / 64, R / 64, 1), 256, 0, stream>>>(
      Vp, Dx, P, R, N_DIM, D_DIM, 0, 0, 0, nullptr);
  // sequential x-scan, independent per batch
  k_scan<<<B_BATCH, 64, 0, stream>>>(P, X);
  // S = X @ X^T per batch: [256,2048]x[256,2048]^T -> [256,256]
  k_gemm_abT<0><<<dim3(T_SEQ / 64, T_SEQ / 64, B_BATCH), 256, 0, stream>>>(
      X, X, S, T_SEQ, T_SEQ, N_DIM,
      (long)T_SEQ * N_DIM, (long)T_SEQ * N_DIM, (long)T_SEQ * T_SEQ, nullptr);
  // a_star = (decay-masked S) @ Vp
  k_astar<<<R, D_DIM, 0, stream>>>(S, Vp, A);
  k_ln<<<R, 64, 0, stream>>>(A, LnA);
  // Yt = relu(LnA @ Dy^T) * relu(X)
  k_gemm_abT<1><<<dim3(N_DIM / 64, R / 64, 1), 256, 0, stream>>>(
      LnA, Dy, Yt, R, N_DIM, D_DIM, 0, 0, 0, X);
  // U = Yt @ E^T : [2048,2048]x[128,2048]^T -> [2048,128]
  k_gemm_abT<0><<<dim3(D_DIM / 64, R / 64, 1), 256, 0, stream>>>(
      Yt, E, U, R, D_DIM, N_DIM, 0, 0, 0, nullptr);
  k_ln<<<R, 64, 0, stream>>>(U, out);
}

// Round 4
// 483.288 us; speedup vs baseline: 1.4680x; 1.3234x over previous
//
#include <hip/hip_runtime.h>

#define T_SEQ 256
#define N_DIM 2048
#define D_DIM 128
#define B_BATCH 8

// ---------------- gather: Vp[r,:] = token_emb[tokens[r]] ----------------
__global__ __launch_bounds__(128) void k_gather(const float* __restrict__ emb,
                                                const int* __restrict__ toks,
                                                float* __restrict__ Vp) {
  int r = blockIdx.x;
  int d = threadIdx.x;
  int tok = toks[r];
  Vp[(long)r * D_DIM + d] = emb[(long)tok * D_DIM + d];
}

// ---------------- generic C[M,N] = A[M,K] @ B[N,K]^T (row-major) --------
// FUSE=1: C = relu(C) * relu(Xr)   (Xr same shape/stride as C)
template <int FUSE>
__global__ __launch_bounds__(256) void k_gemm_abT(
    const float* __restrict__ A, const float* __restrict__ Bm, float* __restrict__ C,
    int M, int N, int K, long sA, long sB, long sC, const float* __restrict__ Xr) {
  constexpr int BM = 64, BN = 64, BK = 16;
  A += (long)blockIdx.z * sA;
  Bm += (long)blockIdx.z * sB;
  C += (long)blockIdx.z * sC;
  const float* Xp = Xr ? Xr + (long)blockIdx.z * sC : nullptr;

  __shared__ float As[BK][BM + 4];
  __shared__ float Bs[BK][BN + 4];
  int tid = threadIdx.x;
  int tx = tid & 15, ty = tid >> 4;
  int row0 = blockIdx.y * BM, col0 = blockIdx.x * BN;
  float acc[4][4] = {};

  for (int k0 = 0; k0 < K; k0 += BK) {
#pragma unroll
    for (int i = 0; i < 4; i++) {
      int idx = tid + i * 256;
      int m = idx >> 4;  // 0..63
      int k = idx & 15;  // 0..15
      As[k][m] = A[(long)(row0 + m) * K + k0 + k];
      Bs[k][m] = Bm[(long)(col0 + m) * K + k0 + k];
    }
    __syncthreads();
#pragma unroll
    for (int k = 0; k < BK; k++) {
      float a[4], b[4];
#pragma unroll
      for (int i = 0; i < 4; i++) a[i] = As[k][ty * 4 + i];
#pragma unroll
      for (int j = 0; j < 4; j++) b[j] = Bs[k][tx * 4 + j];
#pragma unroll
      for (int i = 0; i < 4; i++)
#pragma unroll
        for (int j = 0; j < 4; j++) acc[i][j] += a[i] * b[j];
    }
    __syncthreads();
  }
#pragma unroll
  for (int i = 0; i < 4; i++) {
    long r = row0 + ty * 4 + i;
    long c = col0 + tx * 4;
    long off = r * (long)N + c;
    float4 v = make_float4(acc[i][0], acc[i][1], acc[i][2], acc[i][3]);
    if (FUSE) {
      float4 xv = *(const float4*)(Xp + off);
      v.x = fmaxf(v.x, 0.f) * fmaxf(xv.x, 0.f);
      v.y = fmaxf(v.y, 0.f) * fmaxf(xv.y, 0.f);
      v.z = fmaxf(v.z, 0.f) * fmaxf(xv.z, 0.f);
      v.w = fmaxf(v.w, 0.f) * fmaxf(xv.w, 0.f);
    }
    *(float4*)(C + off) = v;
  }
}

// --------------- DPP wave-64 reduction helpers (VALU, no LDS) -----------
// row_shr:1/2/4/8 then row_bcast:15, row_bcast:31 -> lane 63 holds result.
// Zero-fill from bound_ctrl never reaches lane 63's ancestor chain
// (ancestors 62,61,59,55,47,31 all have valid sources at their stage).
template <int CTRL>
__device__ __forceinline__ float dpp_mov(float v) {
  return __int_as_float(
      __builtin_amdgcn_update_dpp(0, __float_as_int(v), CTRL, 0xF, 0xF, true));
}

__device__ __forceinline__ void wave_reduce_sum_max63(float& s, float& m) {
  s += dpp_mov<0x111>(s);  m = fmaxf(m, dpp_mov<0x111>(m));  // row_shr:1
  s += dpp_mov<0x112>(s);  m = fmaxf(m, dpp_mov<0x112>(m));  // row_shr:2
  s += dpp_mov<0x114>(s);  m = fmaxf(m, dpp_mov<0x114>(m));  // row_shr:4
  s += dpp_mov<0x118>(s);  m = fmaxf(m, dpp_mov<0x118>(m));  // row_shr:8
  s += dpp_mov<0x142>(s);  m = fmaxf(m, dpp_mov<0x142>(m));  // row_bcast:15
  s += dpp_mov<0x143>(s);  m = fmaxf(m, dpp_mov<0x143>(m));  // row_bcast:31
}

// ---------------- sequential x-scan: one block (4 waves) per batch ------
// x_t = thresh(normalize(0.97*x_{t-1} + P_t));  writes dense X[b,t,:]
// 8 elems/thread so a depth-2/3 rotating register prefetch fits in VGPRs.
// Cross-wave reduce: DPP to lane63 -> LDS (parity-double-buffered) ->
// ONE __syncthreads -> broadcast read.
__global__ __launch_bounds__(256) void k_scan(const float* __restrict__ P,
                                              float* __restrict__ X) {
  int b = blockIdx.x;
  int tid = threadIdx.x;
  int wave = tid >> 6;
  int lane = tid & 63;
  __shared__ float red[2][4][2];  // [step parity][wave][{sum,max}]

  const float4* Pv = (const float4*)(P + (long)b * T_SEQ * N_DIM);
  float4* Xv = (float4*)(X + (long)b * T_SEQ * N_DIM);
  const int ROWQ = N_DIM / 4;  // 512 float4 per row; 256 threads x 2 each
  const long o0 = (long)tid * 2, o1 = o0 + 1;

  float x[8];
#pragma unroll
  for (int j = 0; j < 8; j++) x[j] = 0.f;

  auto rowOff = [&](int t) { return (long)(t < T_SEQ ? t : T_SEQ - 1) * ROWQ; };

  auto step = [&](const float4& v0, const float4& v1, int t) {
    float z[8];
    z[0] = 0.97f * x[0] + v0.x;
    z[1] = 0.97f * x[1] + v0.y;
    z[2] = 0.97f * x[2] + v0.z;
    z[3] = 0.97f * x[3] + v0.w;
    z[4] = 0.97f * x[4] + v1.x;
    z[5] = 0.97f * x[5] + v1.y;
    z[6] = 0.97f * x[6] + v1.z;
    z[7] = 0.97f * x[7] + v1.w;
    // per-lane pairwise trees (depth 3)
    float s0 = fabsf(z[0]) + fabsf(z[4]);
    float s1 = fabsf(z[1]) + fabsf(z[5]);
    float s2 = fabsf(z[2]) + fabsf(z[6]);
    float s3 = fabsf(z[3]) + fabsf(z[7]);
    float m0 = fmaxf(z[0], z[4]);
    float m1 = fmaxf(z[1], z[5]);
    float m2 = fmaxf(z[2], z[6]);
    float m3 = fmaxf(z[3], z[7]);
    float s = (s0 + s1) + (s2 + s3);
    float m = fmaxf(fmaxf(m0, m1), fmaxf(m2, m3));
    wave_reduce_sum_max63(s, m);
    int par = t & 1;
    if (lane == 63) {
      red[par][wave][0] = s;
      red[par][wave][1] = m;
    }
    __syncthreads();
    float S = (red[par][0][0] + red[par][1][0]) + (red[par][2][0] + red[par][3][0]);
    float M = fmaxf(fmaxf(red[par][0][1], red[par][1][1]),
                    fmaxf(red[par][2][1], red[par][3][1]));
    float inv = 1.f / (S + 1e-6f);
    float thr = 0.02f * M;  // threshold in un-normalized space (scale-invariant)
#pragma unroll
    for (int j = 0; j < 8; j++) x[j] = (z[j] > thr) ? z[j] * inv : 0.f;
    long rb = (long)t * ROWQ;
    Xv[rb + o0] = make_float4(x[0], x[1], x[2], x[3]);
    Xv[rb + o1] = make_float4(x[4], x[5], x[6], x[7]);
  };

  // rotating 4-buffer register pipeline, prefetch depth 2-3 rows
  float4 A0 = Pv[rowOff(0) + o0], A1 = Pv[rowOff(0) + o1];
  float4 B0 = Pv[rowOff(1) + o0], B1 = Pv[rowOff(1) + o1];
  float4 C0 = Pv[rowOff(2) + o0], C1 = Pv[rowOff(2) + o1];
  float4 D0, D1;

  for (int t = 0; t < T_SEQ; t += 4) {
    D0 = Pv[rowOff(t + 3) + o0];
    D1 = Pv[rowOff(t + 3) + o1];
    step(A0, A1, t);
    A0 = Pv[rowOff(t + 4) + o0];
    A1 = Pv[rowOff(t + 4) + o1];
    step(B0, B1, t + 1);
    B0 = Pv[rowOff(t + 5) + o0];
    B1 = Pv[rowOff(t + 5) + o1];
    step(C0, C1, t + 2);
    C0 = Pv[rowOff(t + 6) + o0];
    C1 = Pv[rowOff(t + 6) + o1];
    step(D0, D1, t + 3);
  }
}

// ------ a_star[b,t,d] = sum_{s<t} 0.97^(t-s) * S[b,t,s] * Vp[b,s,d] -----
__global__ __launch_bounds__(128) void k_astar(const float* __restrict__ S,
                                               const float* __restrict__ Vp,
                                               float* __restrict__ A) {
  int bx = blockIdx.x;
  int b = bx >> 8, t = bx & 255;
  int d = threadIdx.x;
  const float* Sb = S + ((long)b * T_SEQ + t) * T_SEQ;
  const float* Vb = Vp + (long)b * T_SEQ * D_DIM;
  float acc = 0.f;
  float w = 1.f;
  for (int s = t - 1; s >= 0; s--) {
    w *= 0.97f;
    acc += w * Sb[s] * Vb[(long)s * D_DIM + d];
  }
  A[((long)b * T_SEQ + t) * D_DIM + d] = acc;
}

// ------------- row layernorm over D=128 (torch ddof=1 semantics) --------
__global__ __launch_bounds__(64) void k_ln(const float* __restrict__ In,
                                           float* __restrict__ Out) {
  long base = (long)blockIdx.x * D_DIM;
  int lane = threadIdx.x;
  float a = In[base + lane];
  float b = In[base + lane + 64];
  float s = a + b;
#pragma unroll
  for (int off = 32; off >= 1; off >>= 1) s += __shfl_xor(s, off);
  float m = s * (1.f / 128.f);
  float da = a - m, db = b - m;
  float v = da * da + db * db;
#pragma unroll
  for (int off = 32; off >= 1; off >>= 1) v += __shfl_xor(v, off);
  float sd = sqrtf(v * (1.f / 127.f));
  float invs = 1.f / (sd + 1e-6f);
  Out[base + lane] = da * invs;
  Out[base + lane + 64] = db * invs;
}

extern "C" void kernel_launch(void* const* d_in, const int* in_sizes, int n_in,
                              void* d_out, int out_size, void* d_ws, size_t ws_size,
                              hipStream_t stream) {
  const float* E = (const float*)d_in[0];     // [128, 2048]
  const float* Dx = (const float*)d_in[1];    // [2048, 128]
  const float* Dy = (const float*)d_in[2];    // [2048, 128]
  const float* emb = (const float*)d_in[3];   // [131072, 128]
  const int* toks = (const int*)d_in[4];      // [8, 256]
  float* out = (float*)d_out;                 // [8, 256, 128]

  char* ws = (char*)d_ws;
  const size_t MB = 1u << 20;
  float* Vp = (float*)(ws + 0 * MB);    // 1 MB   [2048,128]
  float* P = (float*)(ws + 1 * MB);     // 16 MB  [2048,2048]
  float* X = (float*)(ws + 17 * MB);    // 16 MB  [2048,2048]
  float* S = (float*)(ws + 33 * MB);    // 2 MB   [8,256,256]
  float* A = (float*)(ws + 35 * MB);    // 1 MB   [2048,128]
  float* LnA = (float*)(ws + 36 * MB);  // 1 MB
  float* U = (float*)(ws + 37 * MB);    // 1 MB
  float* Yt = P;                        // reuse P (dead after scan)

  const int R = B_BATCH * T_SEQ;  // 2048

  k_gather<<<R, D_DIM, 0, stream>>>(emb, toks, Vp);
  // P = Vp @ Dx^T : [2048,128]x[2048,128]^T -> [2048,2048]
  k_gemm_abT<0><<<dim3(N_DIM / 64, R / 64, 1), 256, 0, stream>>>(
      Vp, Dx, P, R, N_DIM, D_DIM, 0, 0, 0, nullptr);
  // sequential x-scan, independent per batch
  k_scan<<<B_BATCH, 256, 0, stream>>>(P, X);
  // S = X @ X^T per batch: [256,2048]x[256,2048]^T -> [256,256]
  k_gemm_abT<0><<<dim3(T_SEQ / 64, T_SEQ / 64, B_BATCH), 256, 0, stream>>>(
      X, X, S, T_SEQ, T_SEQ, N_DIM,
      (long)T_SEQ * N_DIM, (long)T_SEQ * N_DIM, (long)T_SEQ * T_SEQ, nullptr);
  // a_star = (decay-masked S) @ Vp
  k_astar<<<R, D_DIM, 0, stream>>>(S, Vp, A);
  k_ln<<<R, 64, 0, stream>>>(A, LnA);
  // Yt = relu(LnA @ Dy^T) * relu(X)
  k_gemm_abT<1><<<dim3(N_DIM / 64, R / 64, 1), 256, 0, stream>>>(
      LnA, Dy, Yt, R, N_DIM, D_DIM, 0, 0, 0, X);
  // U = Yt @ E^T : [2048,2048]x[128,2048]^T -> [2048,128]
  k_gemm_abT<0><<<dim3(D_DIM / 64, R / 64, 1), 256, 0, stream>>>(
      Yt, E, U, R, D_DIM, N_DIM, 0, 0, 0, nullptr);
  k_ln<<<R, 64, 0, stream>>>(U, out);
}

// Round 5
// 362.190 us; speedup vs baseline: 1.9588x; 1.3343x over previous
//
#include <hip/hip_runtime.h>

#define T_SEQ 256
#define N_DIM 2048
#define D_DIM 128
#define B_BATCH 8

// ---------------- gather: Vp[r,:] = token_emb[tokens[r]] ----------------
__global__ __launch_bounds__(128) void k_gather(const float* __restrict__ emb,
                                                const int* __restrict__ toks,
                                                float* __restrict__ Vp) {
  int r = blockIdx.x;
  int d = threadIdx.x;
  int tok = toks[r];
  Vp[(long)r * D_DIM + d] = emb[(long)tok * D_DIM + d];
}

// ---------------- zero fill (float4 granular) ---------------------------
__global__ __launch_bounds__(256) void k_zero(float* __restrict__ p, long n4) {
  long i = (long)blockIdx.x * blockDim.x + threadIdx.x;
  if (i < n4) ((float4*)p)[i] = make_float4(0.f, 0.f, 0.f, 0.f);
}

// ---------------- generic C[M,N] = A[M,K] @ B[N,K]^T (row-major) --------
// FUSE=1: C = relu(C) * relu(Xr)   (Xr same shape/stride as C)
template <int FUSE>
__global__ __launch_bounds__(256) void k_gemm_abT(
    const float* __restrict__ A, const float* __restrict__ Bm, float* __restrict__ C,
    int M, int N, int K, long sA, long sB, long sC, const float* __restrict__ Xr) {
  constexpr int BM = 64, BN = 64, BK = 16;
  A += (long)blockIdx.z * sA;
  Bm += (long)blockIdx.z * sB;
  C += (long)blockIdx.z * sC;
  const float* Xp = Xr ? Xr + (long)blockIdx.z * sC : nullptr;

  __shared__ float As[BK][BM + 4];
  __shared__ float Bs[BK][BN + 4];
  int tid = threadIdx.x;
  int tx = tid & 15, ty = tid >> 4;
  int row0 = blockIdx.y * BM, col0 = blockIdx.x * BN;
  float acc[4][4] = {};

  for (int k0 = 0; k0 < K; k0 += BK) {
#pragma unroll
    for (int i = 0; i < 4; i++) {
      int idx = tid + i * 256;
      int m = idx >> 4;  // 0..63
      int k = idx & 15;  // 0..15
      As[k][m] = A[(long)(row0 + m) * K + k0 + k];
      Bs[k][m] = Bm[(long)(col0 + m) * K + k0 + k];
    }
    __syncthreads();
#pragma unroll
    for (int k = 0; k < BK; k++) {
      float a[4], b[4];
#pragma unroll
      for (int i = 0; i < 4; i++) a[i] = As[k][ty * 4 + i];
#pragma unroll
      for (int j = 0; j < 4; j++) b[j] = Bs[k][tx * 4 + j];
#pragma unroll
      for (int i = 0; i < 4; i++)
#pragma unroll
        for (int j = 0; j < 4; j++) acc[i][j] += a[i] * b[j];
    }
    __syncthreads();
  }
#pragma unroll
  for (int i = 0; i < 4; i++) {
    long r = row0 + ty * 4 + i;
    long c = col0 + tx * 4;
    long off = r * (long)N + c;
    float4 v = make_float4(acc[i][0], acc[i][1], acc[i][2], acc[i][3]);
    if (FUSE) {
      float4 xv = *(const float4*)(Xp + off);
      v.x = fmaxf(v.x, 0.f) * fmaxf(xv.x, 0.f);
      v.y = fmaxf(v.y, 0.f) * fmaxf(xv.y, 0.f);
      v.z = fmaxf(v.z, 0.f) * fmaxf(xv.z, 0.f);
      v.w = fmaxf(v.w, 0.f) * fmaxf(xv.w, 0.f);
    }
    *(float4*)(C + off) = v;
  }
}

// ------- split-K variant: C += A_chunk @ B_chunk^T via f32 atomics ------
// z = batch * KS + ks. TRI=1: skip tiles strictly above the diagonal
// (only s<t entries are ever read downstream).
template <int TRI>
__global__ __launch_bounds__(256) void k_gemm_abT_splitk(
    const float* __restrict__ A, const float* __restrict__ Bm, float* __restrict__ C,
    int M, int N, int K, int KS, long sA, long sB, long sC) {
  constexpr int BM = 64, BN = 64, BK = 16;
  int bz = blockIdx.z;
  int batch = bz / KS, ks = bz - batch * KS;
  A += (long)batch * sA;
  Bm += (long)batch * sB;
  C += (long)batch * sC;
  int row0 = blockIdx.y * BM, col0 = blockIdx.x * BN;
  if (TRI && col0 > row0) return;  // tile entirely in s>=t region
  int kLen = K / KS, k0beg = ks * kLen;

  __shared__ float As[BK][BM + 4];
  __shared__ float Bs[BK][BN + 4];
  int tid = threadIdx.x;
  int tx = tid & 15, ty = tid >> 4;
  float acc[4][4] = {};

  for (int k0 = k0beg; k0 < k0beg + kLen; k0 += BK) {
#pragma unroll
    for (int i = 0; i < 4; i++) {
      int idx = tid + i * 256;
      int m = idx >> 4;
      int k = idx & 15;
      As[k][m] = A[(long)(row0 + m) * K + k0 + k];
      Bs[k][m] = Bm[(long)(col0 + m) * K + k0 + k];
    }
    __syncthreads();
#pragma unroll
    for (int k = 0; k < BK; k++) {
      float a[4], b[4];
#pragma unroll
      for (int i = 0; i < 4; i++) a[i] = As[k][ty * 4 + i];
#pragma unroll
      for (int j = 0; j < 4; j++) b[j] = Bs[k][tx * 4 + j];
#pragma unroll
      for (int i = 0; i < 4; i++)
#pragma unroll
        for (int j = 0; j < 4; j++) acc[i][j] += a[i] * b[j];
    }
    __syncthreads();
  }
#pragma unroll
  for (int i = 0; i < 4; i++) {
    long r = row0 + ty * 4 + i;
    long c = col0 + tx * 4;
    float* cp = C + r * (long)N + c;
#pragma unroll
    for (int j = 0; j < 4; j++) unsafeAtomicAdd(cp + j, acc[i][j]);
  }
}

// --------------- DPP wave-64 reduction helpers (VALU, no LDS) -----------
template <int CTRL>
__device__ __forceinline__ float dpp_mov(float v) {
  return __int_as_float(
      __builtin_amdgcn_update_dpp(0, __float_as_int(v), CTRL, 0xF, 0xF, true));
}

__device__ __forceinline__ void wave_reduce_sum_max63(float& s, float& m) {
  s += dpp_mov<0x111>(s);  m = fmaxf(m, dpp_mov<0x111>(m));  // row_shr:1
  s += dpp_mov<0x112>(s);  m = fmaxf(m, dpp_mov<0x112>(m));  // row_shr:2
  s += dpp_mov<0x114>(s);  m = fmaxf(m, dpp_mov<0x114>(m));  // row_shr:4
  s += dpp_mov<0x118>(s);  m = fmaxf(m, dpp_mov<0x118>(m));  // row_shr:8
  s += dpp_mov<0x142>(s);  m = fmaxf(m, dpp_mov<0x142>(m));  // row_bcast:15
  s += dpp_mov<0x143>(s);  m = fmaxf(m, dpp_mov<0x143>(m));  // row_bcast:31
}

// ---------------- sequential x-scan: one block (4 waves) per batch ------
__global__ __launch_bounds__(256) void k_scan(const float* __restrict__ P,
                                              float* __restrict__ X) {
  int b = blockIdx.x;
  int tid = threadIdx.x;
  int wave = tid >> 6;
  int lane = tid & 63;
  __shared__ float red[2][4][2];  // [step parity][wave][{sum,max}]

  const float4* Pv = (const float4*)(P + (long)b * T_SEQ * N_DIM);
  float4* Xv = (float4*)(X + (long)b * T_SEQ * N_DIM);
  const int ROWQ = N_DIM / 4;  // 512 float4 per row; 256 threads x 2 each
  const long o0 = (long)tid * 2, o1 = o0 + 1;

  float x[8];
#pragma unroll
  for (int j = 0; j < 8; j++) x[j] = 0.f;

  auto rowOff = [&](int t) { return (long)(t < T_SEQ ? t : T_SEQ - 1) * ROWQ; };

  auto step = [&](const float4& v0, const float4& v1, int t) {
    float z[8];
    z[0] = 0.97f * x[0] + v0.x;
    z[1] = 0.97f * x[1] + v0.y;
    z[2] = 0.97f * x[2] + v0.z;
    z[3] = 0.97f * x[3] + v0.w;
    z[4] = 0.97f * x[4] + v1.x;
    z[5] = 0.97f * x[5] + v1.y;
    z[6] = 0.97f * x[6] + v1.z;
    z[7] = 0.97f * x[7] + v1.w;
    float s0 = fabsf(z[0]) + fabsf(z[4]);
    float s1 = fabsf(z[1]) + fabsf(z[5]);
    float s2 = fabsf(z[2]) + fabsf(z[6]);
    float s3 = fabsf(z[3]) + fabsf(z[7]);
    float m0 = fmaxf(z[0], z[4]);
    float m1 = fmaxf(z[1], z[5]);
    float m2 = fmaxf(z[2], z[6]);
    float m3 = fmaxf(z[3], z[7]);
    float s = (s0 + s1) + (s2 + s3);
    float m = fmaxf(fmaxf(m0, m1), fmaxf(m2, m3));
    wave_reduce_sum_max63(s, m);
    int par = t & 1;
    if (lane == 63) {
      red[par][wave][0] = s;
      red[par][wave][1] = m;
    }
    __syncthreads();
    float S = (red[par][0][0] + red[par][1][0]) + (red[par][2][0] + red[par][3][0]);
    float M = fmaxf(fmaxf(red[par][0][1], red[par][1][1]),
                    fmaxf(red[par][2][1], red[par][3][1]));
    float inv = 1.f / (S + 1e-6f);
    float thr = 0.02f * M;  // threshold in un-normalized space (scale-invariant)
#pragma unroll
    for (int j = 0; j < 8; j++) x[j] = (z[j] > thr) ? z[j] * inv : 0.f;
    long rb = (long)t * ROWQ;
    Xv[rb + o0] = make_float4(x[0], x[1], x[2], x[3]);
    Xv[rb + o1] = make_float4(x[4], x[5], x[6], x[7]);
  };

  // rotating 4-buffer register pipeline, prefetch depth 2-3 rows
  float4 A0 = Pv[rowOff(0) + o0], A1 = Pv[rowOff(0) + o1];
  float4 B0 = Pv[rowOff(1) + o0], B1 = Pv[rowOff(1) + o1];
  float4 C0 = Pv[rowOff(2) + o0], C1 = Pv[rowOff(2) + o1];
  float4 D0, D1;

  for (int t = 0; t < T_SEQ; t += 4) {
    D0 = Pv[rowOff(t + 3) + o0];
    D1 = Pv[rowOff(t + 3) + o1];
    step(A0, A1, t);
    A0 = Pv[rowOff(t + 4) + o0];
    A1 = Pv[rowOff(t + 4) + o1];
    step(B0, B1, t + 1);
    B0 = Pv[rowOff(t + 5) + o0];
    B1 = Pv[rowOff(t + 5) + o1];
    step(C0, C1, t + 2);
    C0 = Pv[rowOff(t + 6) + o0];
    C1 = Pv[rowOff(t + 6) + o1];
    step(D0, D1, t + 3);
  }
}

// ------ a_star[b,t,d] = sum_{s<t} 0.97^(t-s) * S[b,t,s] * Vp[b,s,d] -----
__global__ __launch_bounds__(128) void k_astar(const float* __restrict__ S,
                                               const float* __restrict__ Vp,
                                               float* __restrict__ A) {
  int bx = blockIdx.x;
  int b = bx >> 8, t = bx & 255;
  int d = threadIdx.x;
  const float* Sb = S + ((long)b * T_SEQ + t) * T_SEQ;
  const float* Vb = Vp + (long)b * T_SEQ * D_DIM;
  float acc = 0.f;
  float w = 1.f;
  for (int s = t - 1; s >= 0; s--) {
    w *= 0.97f;
    acc += w * Sb[s] * Vb[(long)s * D_DIM + d];
  }
  A[((long)b * T_SEQ + t) * D_DIM + d] = acc;
}

// ------------- row layernorm over D=128 (torch ddof=1 semantics) --------
__global__ __launch_bounds__(64) void k_ln(const float* __restrict__ In,
                                           float* __restrict__ Out) {
  long base = (long)blockIdx.x * D_DIM;
  int lane = threadIdx.x;
  float a = In[base + lane];
  float b = In[base + lane + 64];
  float s = a + b;
#pragma unroll
  for (int off = 32; off >= 1; off >>= 1) s += __shfl_xor(s, off);
  float m = s * (1.f / 128.f);
  float da = a - m, db = b - m;
  float v = da * da + db * db;
#pragma unroll
  for (int off = 32; off >= 1; off >>= 1) v += __shfl_xor(v, off);
  float sd = sqrtf(v * (1.f / 127.f));
  float invs = 1.f / (sd + 1e-6f);
  Out[base + lane] = da * invs;
  Out[base + lane + 64] = db * invs;
}

extern "C" void kernel_launch(void* const* d_in, const int* in_sizes, int n_in,
                              void* d_out, int out_size, void* d_ws, size_t ws_size,
                              hipStream_t stream) {
  const float* E = (const float*)d_in[0];     // [128, 2048]
  const float* Dx = (const float*)d_in[1];    // [2048, 128]
  const float* Dy = (const float*)d_in[2];    // [2048, 128]
  const float* emb = (const float*)d_in[3];   // [131072, 128]
  const int* toks = (const int*)d_in[4];      // [8, 256]
  float* out = (float*)d_out;                 // [8, 256, 128]

  char* ws = (char*)d_ws;
  const size_t MB = 1u << 20;
  float* Vp = (float*)(ws + 0 * MB);    // 1 MB   [2048,128]
  float* P = (float*)(ws + 1 * MB);     // 16 MB  [2048,2048]
  float* X = (float*)(ws + 17 * MB);    // 16 MB  [2048,2048]
  float* S = (float*)(ws + 33 * MB);    // 2 MB   [8,256,256]
  float* A = (float*)(ws + 35 * MB);    // 1 MB   [2048,128]
  float* LnA = (float*)(ws + 36 * MB);  // 1 MB
  float* U = (float*)(ws + 37 * MB);    // 1 MB
  float* Yt = P;                        // reuse P (dead after scan)

  const int R = B_BATCH * T_SEQ;  // 2048

  k_gather<<<R, D_DIM, 0, stream>>>(emb, toks, Vp);
  // P = Vp @ Dx^T : [2048,128]x[2048,128]^T -> [2048,2048]
  k_gemm_abT<0><<<dim3(N_DIM / 64, R / 64, 1), 256, 0, stream>>>(
      Vp, Dx, P, R, N_DIM, D_DIM, 0, 0, 0, nullptr);
  // sequential x-scan, independent per batch
  k_scan<<<B_BATCH, 256, 0, stream>>>(P, X);
  // zero split-K accumulators (ws is poisoned before every launch)
  k_zero<<<(B_BATCH * T_SEQ * T_SEQ / 4 + 255) / 256, 256, 0, stream>>>(
      S, B_BATCH * T_SEQ * T_SEQ / 4);
  k_zero<<<(R * D_DIM / 4 + 255) / 256, 256, 0, stream>>>(U, R * D_DIM / 4);
  // S = X @ X^T per batch (lower-triangular tiles only), split-K x4
  k_gemm_abT_splitk<1><<<dim3(T_SEQ / 64, T_SEQ / 64, B_BATCH * 4), 256, 0, stream>>>(
      X, X, S, T_SEQ, T_SEQ, N_DIM, 4,
      (long)T_SEQ * N_DIM, (long)T_SEQ * N_DIM, (long)T_SEQ * T_SEQ);
  // a_star = (decay-masked S) @ Vp
  k_astar<<<R, D_DIM, 0, stream>>>(S, Vp, A);
  k_ln<<<R, 64, 0, stream>>>(A, LnA);
  // Yt = relu(LnA @ Dy^T) * relu(X)
  k_gemm_abT<1><<<dim3(N_DIM / 64, R / 64, 1), 256, 0, stream>>>(
      LnA, Dy, Yt, R, N_DIM, D_DIM, 0, 0, 0, X);
  // U = Yt @ E^T : [2048,2048]x[128,2048]^T -> [2048,128], split-K x8
  k_gemm_abT_splitk<0><<<dim3(D_DIM / 64, R / 64, 8), 256, 0, stream>>>(
      Yt, E, U, R, D_DIM, N_DIM, 8, 0, 0, 0);
  k_ln<<<R, 64, 0, stream>>>(U, out);
}

// Round 6
// 361.723 us; speedup vs baseline: 1.9613x; 1.0013x over previous
//
#include <hip/hip_runtime.h>

#define T_SEQ 256
#define N_DIM 2048
#define D_DIM 128
#define B_BATCH 8

// ---------------- gather: Vp[r,:] = token_emb[tokens[r]] ----------------
__global__ __launch_bounds__(128) void k_gather(const float* __restrict__ emb,
                                                const int* __restrict__ toks,
                                                float* __restrict__ Vp) {
  int r = blockIdx.x;
  int d = threadIdx.x;
  int tok = toks[r];
  Vp[(long)r * D_DIM + d] = emb[(long)tok * D_DIM + d];
}

// ---------------- zero fill (float4 granular) ---------------------------
__global__ __launch_bounds__(256) void k_zero(float* __restrict__ p, long n4) {
  long i = (long)blockIdx.x * blockDim.x + threadIdx.x;
  if (i < n4) ((float4*)p)[i] = make_float4(0.f, 0.f, 0.f, 0.f);
}

// ---------------- generic C[M,N] = A[M,K] @ B[N,K]^T (row-major) --------
// FUSE=1: C = relu(C) * relu(Xr)   (Xr same shape/stride as C)
template <int FUSE>
__global__ __launch_bounds__(256) void k_gemm_abT(
    const float* __restrict__ A, const float* __restrict__ Bm, float* __restrict__ C,
    int M, int N, int K, long sA, long sB, long sC, const float* __restrict__ Xr) {
  constexpr int BM = 64, BN = 64, BK = 16;
  A += (long)blockIdx.z * sA;
  Bm += (long)blockIdx.z * sB;
  C += (long)blockIdx.z * sC;
  const float* Xp = Xr ? Xr + (long)blockIdx.z * sC : nullptr;

  __shared__ float As[BK][BM + 4];
  __shared__ float Bs[BK][BN + 4];
  int tid = threadIdx.x;
  int tx = tid & 15, ty = tid >> 4;
  int row0 = blockIdx.y * BM, col0 = blockIdx.x * BN;
  float acc[4][4] = {};

  for (int k0 = 0; k0 < K; k0 += BK) {
#pragma unroll
    for (int i = 0; i < 4; i++) {
      int idx = tid + i * 256;
      int m = idx >> 4;  // 0..63
      int k = idx & 15;  // 0..15
      As[k][m] = A[(long)(row0 + m) * K + k0 + k];
      Bs[k][m] = Bm[(long)(col0 + m) * K + k0 + k];
    }
    __syncthreads();
#pragma unroll
    for (int k = 0; k < BK; k++) {
      float a[4], b[4];
#pragma unroll
      for (int i = 0; i < 4; i++) a[i] = As[k][ty * 4 + i];
#pragma unroll
      for (int j = 0; j < 4; j++) b[j] = Bs[k][tx * 4 + j];
#pragma unroll
      for (int i = 0; i < 4; i++)
#pragma unroll
        for (int j = 0; j < 4; j++) acc[i][j] += a[i] * b[j];
    }
    __syncthreads();
  }
#pragma unroll
  for (int i = 0; i < 4; i++) {
    long r = row0 + ty * 4 + i;
    long c = col0 + tx * 4;
    long off = r * (long)N + c;
    float4 v = make_float4(acc[i][0], acc[i][1], acc[i][2], acc[i][3]);
    if (FUSE) {
      float4 xv = *(const float4*)(Xp + off);
      v.x = fmaxf(v.x, 0.f) * fmaxf(xv.x, 0.f);
      v.y = fmaxf(v.y, 0.f) * fmaxf(xv.y, 0.f);
      v.z = fmaxf(v.z, 0.f) * fmaxf(xv.z, 0.f);
      v.w = fmaxf(v.w, 0.f) * fmaxf(xv.w, 0.f);
    }
    *(float4*)(C + off) = v;
  }
}

// ------- split-K variant: C += A_chunk @ B_chunk^T via f32 atomics ------
// z = batch * KS + ks. TRI=1: skip tiles strictly above the diagonal
// (only s<t entries are ever read downstream).
template <int TRI>
__global__ __launch_bounds__(256) void k_gemm_abT_splitk(
    const float* __restrict__ A, const float* __restrict__ Bm, float* __restrict__ C,
    int M, int N, int K, int KS, long sA, long sB, long sC) {
  constexpr int BM = 64, BN = 64, BK = 16;
  int bz = blockIdx.z;
  int batch = bz / KS, ks = bz - batch * KS;
  A += (long)batch * sA;
  Bm += (long)batch * sB;
  C += (long)batch * sC;
  int row0 = blockIdx.y * BM, col0 = blockIdx.x * BN;
  if (TRI && col0 > row0) return;  // tile entirely in s>=t region
  int kLen = K / KS, k0beg = ks * kLen;

  __shared__ float As[BK][BM + 4];
  __shared__ float Bs[BK][BN + 4];
  int tid = threadIdx.x;
  int tx = tid & 15, ty = tid >> 4;
  float acc[4][4] = {};

  for (int k0 = k0beg; k0 < k0beg + kLen; k0 += BK) {
#pragma unroll
    for (int i = 0; i < 4; i++) {
      int idx = tid + i * 256;
      int m = idx >> 4;
      int k = idx & 15;
      As[k][m] = A[(long)(row0 + m) * K + k0 + k];
      Bs[k][m] = Bm[(long)(col0 + m) * K + k0 + k];
    }
    __syncthreads();
#pragma unroll
    for (int k = 0; k < BK; k++) {
      float a[4], b[4];
#pragma unroll
      for (int i = 0; i < 4; i++) a[i] = As[k][ty * 4 + i];
#pragma unroll
      for (int j = 0; j < 4; j++) b[j] = Bs[k][tx * 4 + j];
#pragma unroll
      for (int i = 0; i < 4; i++)
#pragma unroll
        for (int j = 0; j < 4; j++) acc[i][j] += a[i] * b[j];
    }
    __syncthreads();
  }
#pragma unroll
  for (int i = 0; i < 4; i++) {
    long r = row0 + ty * 4 + i;
    long c = col0 + tx * 4;
    float* cp = C + r * (long)N + c;
#pragma unroll
    for (int j = 0; j < 4; j++) unsafeAtomicAdd(cp + j, acc[i][j]);
  }
}

// --------------- DPP wave-64 reduction helpers (VALU, no LDS) -----------
template <int CTRL>
__device__ __forceinline__ float dpp_mov(float v) {
  return __int_as_float(
      __builtin_amdgcn_update_dpp(0, __float_as_int(v), CTRL, 0xF, 0xF, true));
}

__device__ __forceinline__ void wave_reduce_sum_max63(float& s, float& m) {
  s += dpp_mov<0x111>(s);  m = fmaxf(m, dpp_mov<0x111>(m));  // row_shr:1
  s += dpp_mov<0x112>(s);  m = fmaxf(m, dpp_mov<0x112>(m));  // row_shr:2
  s += dpp_mov<0x114>(s);  m = fmaxf(m, dpp_mov<0x114>(m));  // row_shr:4
  s += dpp_mov<0x118>(s);  m = fmaxf(m, dpp_mov<0x118>(m));  // row_shr:8
  s += dpp_mov<0x142>(s);  m = fmaxf(m, dpp_mov<0x142>(m));  // row_bcast:15
  s += dpp_mov<0x143>(s);  m = fmaxf(m, dpp_mov<0x143>(m));  // row_bcast:31
}

__device__ __forceinline__ float wave_sum63(float s) {
  s += dpp_mov<0x111>(s);
  s += dpp_mov<0x112>(s);
  s += dpp_mov<0x114>(s);
  s += dpp_mov<0x118>(s);
  s += dpp_mov<0x142>(s);
  s += dpp_mov<0x143>(s);
  return s;
}

// ---------------- sequential x-scan: one block (4 waves) per batch ------
// Register prefetch depth 3; asm memory-clobbers pin the loads in place
// (compiler may legally sink read-only loads across __syncthreads, which
// it did in rounds 2-5 -> VGPR_Count 32-68 and exposed load latency).
__global__ __launch_bounds__(256) void k_scan(const float* __restrict__ P,
                                              float* __restrict__ X) {
  int b = blockIdx.x;
  int tid = threadIdx.x;
  int wave = tid >> 6;
  int lane = tid & 63;
  __shared__ float red[2][4][2];  // [step parity][wave][{sum,max}]

  const float4* Pv = (const float4*)(P + (long)b * T_SEQ * N_DIM);
  float4* Xv = (float4*)(X + (long)b * T_SEQ * N_DIM);
  const int ROWQ = N_DIM / 4;  // 512 float4 per row; 256 threads x 2 each
  const long o0 = (long)tid * 2, o1 = o0 + 1;

  float x[8];
#pragma unroll
  for (int j = 0; j < 8; j++) x[j] = 0.f;

  auto rowOff = [&](int t) { return (long)(t < T_SEQ ? t : T_SEQ - 1) * ROWQ; };

  auto step = [&](const float4& v0, const float4& v1, int t) {
    float z[8];
    z[0] = 0.97f * x[0] + v0.x;
    z[1] = 0.97f * x[1] + v0.y;
    z[2] = 0.97f * x[2] + v0.z;
    z[3] = 0.97f * x[3] + v0.w;
    z[4] = 0.97f * x[4] + v1.x;
    z[5] = 0.97f * x[5] + v1.y;
    z[6] = 0.97f * x[6] + v1.z;
    z[7] = 0.97f * x[7] + v1.w;
    float s0 = fabsf(z[0]) + fabsf(z[4]);
    float s1 = fabsf(z[1]) + fabsf(z[5]);
    float s2 = fabsf(z[2]) + fabsf(z[6]);
    float s3 = fabsf(z[3]) + fabsf(z[7]);
    float m0 = fmaxf(z[0], z[4]);
    float m1 = fmaxf(z[1], z[5]);
    float m2 = fmaxf(z[2], z[6]);
    float m3 = fmaxf(z[3], z[7]);
    float s = (s0 + s1) + (s2 + s3);
    float m = fmaxf(fmaxf(m0, m1), fmaxf(m2, m3));
    wave_reduce_sum_max63(s, m);
    int par = t & 1;
    if (lane == 63) {
      red[par][wave][0] = s;
      red[par][wave][1] = m;
    }
    __syncthreads();
    float S = (red[par][0][0] + red[par][1][0]) + (red[par][2][0] + red[par][3][0]);
    float M = fmaxf(fmaxf(red[par][0][1], red[par][1][1]),
                    fmaxf(red[par][2][1], red[par][3][1]));
    float inv = 1.f / (S + 1e-6f);
    float thr = 0.02f * M;  // threshold in un-normalized space (scale-invariant)
#pragma unroll
    for (int j = 0; j < 8; j++) x[j] = (z[j] > thr) ? z[j] * inv : 0.f;
    long rb = (long)t * ROWQ;
    Xv[rb + o0] = make_float4(x[0], x[1], x[2], x[3]);
    Xv[rb + o1] = make_float4(x[4], x[5], x[6], x[7]);
  };

  // rotating 4-buffer register pipeline, prefetch depth 3 rows
  float4 A0 = Pv[rowOff(0) + o0], A1 = Pv[rowOff(0) + o1];
  float4 B0 = Pv[rowOff(1) + o0], B1 = Pv[rowOff(1) + o1];
  float4 C0 = Pv[rowOff(2) + o0], C1 = Pv[rowOff(2) + o1];
  asm volatile("" ::: "memory");  // pin prologue loads above this point
  float4 D0, D1;

  for (int t = 0; t < T_SEQ; t += 4) {
    D0 = Pv[rowOff(t + 3) + o0];
    D1 = Pv[rowOff(t + 3) + o1];
    asm volatile("" ::: "memory");  // loads may not sink below
    step(A0, A1, t);
    A0 = Pv[rowOff(t + 4) + o0];
    A1 = Pv[rowOff(t + 4) + o1];
    asm volatile("" ::: "memory");
    step(B0, B1, t + 1);
    B0 = Pv[rowOff(t + 5) + o0];
    B1 = Pv[rowOff(t + 5) + o1];
    asm volatile("" ::: "memory");
    step(C0, C1, t + 2);
    C0 = Pv[rowOff(t + 6) + o0];
    C1 = Pv[rowOff(t + 6) + o1];
    asm volatile("" ::: "memory");
    step(D0, D1, t + 3);
  }
}

// -- a_star[b,t,d] = sum_{s<t} 0.97^(t-s)*S[b,t,s]*Vp[b,s,d], then LN ----
// Fused row layernorm over D=128 (torch ddof=1) across the 2 waves.
__global__ __launch_bounds__(128) void k_astar_ln(const float* __restrict__ S,
                                                  const float* __restrict__ Vp,
                                                  float* __restrict__ LnA) {
  int bx = blockIdx.x;
  int b = bx >> 8, t = bx & 255;
  int d = threadIdx.x;
  int wave = d >> 6, lane = d & 63;
  __shared__ float redS[2], redV[2];
  const float* Sb = S + ((long)b * T_SEQ + t) * T_SEQ;
  const float* Vb = Vp + (long)b * T_SEQ * D_DIM;
  float acc = 0.f;
  float w = 1.f;
  for (int s = t - 1; s >= 0; s--) {
    w *= 0.97f;
    acc += w * Sb[s] * Vb[(long)s * D_DIM + d];
  }
  // layernorm over the 128 threads
  float s1 = wave_sum63(acc);
  if (lane == 63) redS[wave] = s1;
  __syncthreads();
  float mean = (redS[0] + redS[1]) * (1.f / 128.f);
  float dv = acc - mean;
  float v = wave_sum63(dv * dv);
  if (lane == 63) redV[wave] = v;
  __syncthreads();
  float sd = sqrtf((redV[0] + redV[1]) * (1.f / 127.f));
  LnA[((long)b * T_SEQ + t) * D_DIM + d] = dv / (sd + 1e-6f);
}

// ------------- row layernorm over D=128 (torch ddof=1 semantics) --------
__global__ __launch_bounds__(64) void k_ln(const float* __restrict__ In,
                                           float* __restrict__ Out) {
  long base = (long)blockIdx.x * D_DIM;
  int lane = threadIdx.x;
  float a = In[base + lane];
  float b = In[base + lane + 64];
  float s = a + b;
#pragma unroll
  for (int off = 32; off >= 1; off >>= 1) s += __shfl_xor(s, off);
  float m = s * (1.f / 128.f);
  float da = a - m, db = b - m;
  float v = da * da + db * db;
#pragma unroll
  for (int off = 32; off >= 1; off >>= 1) v += __shfl_xor(v, off);
  float sd = sqrtf(v * (1.f / 127.f));
  float invs = 1.f / (sd + 1e-6f);
  Out[base + lane] = da * invs;
  Out[base + lane + 64] = db * invs;
}

extern "C" void kernel_launch(void* const* d_in, const int* in_sizes, int n_in,
                              void* d_out, int out_size, void* d_ws, size_t ws_size,
                              hipStream_t stream) {
  const float* E = (const float*)d_in[0];     // [128, 2048]
  const float* Dx = (const float*)d_in[1];    // [2048, 128]
  const float* Dy = (const float*)d_in[2];    // [2048, 128]
  const float* emb = (const float*)d_in[3];   // [131072, 128]
  const int* toks = (const int*)d_in[4];      // [8, 256]
  float* out = (float*)d_out;                 // [8, 256, 128]

  char* ws = (char*)d_ws;
  const size_t MB = 1u << 20;
  float* Vp = (float*)(ws + 0 * MB);    // 1 MB   [2048,128]
  float* P = (float*)(ws + 1 * MB);     // 16 MB  [2048,2048]
  float* X = (float*)(ws + 17 * MB);    // 16 MB  [2048,2048]
  float* S = (float*)(ws + 33 * MB);    // 2 MB   [8,256,256]   } contiguous
  float* U = (float*)(ws + 35 * MB);    // 1 MB   [2048,128]    } zero range
  float* LnA = (float*)(ws + 36 * MB);  // 1 MB
  float* Yt = P;                        // reuse P (dead after scan)

  const int R = B_BATCH * T_SEQ;  // 2048

  k_gather<<<R, D_DIM, 0, stream>>>(emb, toks, Vp);
  // P = Vp @ Dx^T : [2048,128]x[2048,128]^T -> [2048,2048]
  k_gemm_abT<0><<<dim3(N_DIM / 64, R / 64, 1), 256, 0, stream>>>(
      Vp, Dx, P, R, N_DIM, D_DIM, 0, 0, 0, nullptr);
  // sequential x-scan, independent per batch
  k_scan<<<B_BATCH, 256, 0, stream>>>(P, X);
  // zero split-K accumulators S+U in one contiguous 3MB clear
  k_zero<<<768, 256, 0, stream>>>(S, 3L * MB / 16);
  // S = X @ X^T per batch (lower-triangular tiles only), split-K x8
  k_gemm_abT_splitk<1><<<dim3(T_SEQ / 64, T_SEQ / 64, B_BATCH * 8), 256, 0, stream>>>(
      X, X, S, T_SEQ, T_SEQ, N_DIM, 8,
      (long)T_SEQ * N_DIM, (long)T_SEQ * N_DIM, (long)T_SEQ * T_SEQ);
  // a_star = (decay-masked S) @ Vp, fused layernorm
  k_astar_ln<<<R, D_DIM, 0, stream>>>(S, Vp, LnA);
  // Yt = relu(LnA @ Dy^T) * relu(X)
  k_gemm_abT<1><<<dim3(N_DIM / 64, R / 64, 1), 256, 0, stream>>>(
      LnA, Dy, Yt, R, N_DIM, D_DIM, 0, 0, 0, X);
  // U = Yt @ E^T : [2048,2048]x[128,2048]^T -> [2048,128], split-K x8
  k_gemm_abT_splitk<0><<<dim3(D_DIM / 64, R / 64, 8), 256, 0, stream>>>(
      Yt, E, U, R, D_DIM, N_DIM, 8, 0, 0, 0);
  k_ln<<<R, 64, 0, stream>>>(U, out);
}

// Round 10
// 297.857 us; speedup vs baseline: 2.3818x; 1.2144x over previous
//
#include <hip/hip_runtime.h>

typedef unsigned int u32;
typedef unsigned short u16;

#define T_SEQ 256
#define N_DIM 2048
#define D_DIM 128
#define B_BATCH 8

typedef __attribute__((ext_vector_type(8))) short bfrag;   // 8 bf16 (4 VGPRs)
typedef __attribute__((ext_vector_type(4))) float f4acc;   // 4 f32 acc

__device__ __forceinline__ u16 f2bf(float f) {  // RNE
  u32 u = __float_as_uint(f);
  return (u16)((u + 0x7FFFu + ((u >> 16) & 1u)) >> 16);
}
__device__ __forceinline__ float bf2f(u16 h) { return __uint_as_float(((u32)h) << 16); }

// ---------------- gather: Vp[r,:] = token_emb[tokens[r]] ----------------
__global__ __launch_bounds__(128) void k_gather(const float* __restrict__ emb,
                                                const int* __restrict__ toks,
                                                float* __restrict__ Vp) {
  int r = blockIdx.x;
  int d = threadIdx.x;
  int tok = toks[r];
  Vp[(long)r * D_DIM + d] = emb[(long)tok * D_DIM + d];
}

// ---------------- f32 -> bf16 cast (grid-stride) ------------------------
__global__ __launch_bounds__(256) void k_cast(const float* __restrict__ src,
                                              u16* __restrict__ dst, int n) {
  for (int i = blockIdx.x * 256 + threadIdx.x; i < n; i += gridDim.x * 256)
    dst[i] = f2bf(src[i]);
}

// ---------------- zero fill (float4 granular) ---------------------------
__global__ __launch_bounds__(256) void k_zero(float* __restrict__ p, long n4) {
  long i = (long)blockIdx.x * blockDim.x + threadIdx.x;
  if (i < n4) ((float4*)p)[i] = make_float4(0.f, 0.f, 0.f, 0.f);
}

// ---------------- f32 C = A[M,K] @ B[N,K]^T (for P only; K=128) ---------
__global__ __launch_bounds__(256) void k_gemm_abT(
    const float* __restrict__ A, const float* __restrict__ Bm, float* __restrict__ C,
    int M, int N, int K) {
  constexpr int BM = 64, BN = 64, BK = 16;
  __shared__ float As[BK][BM + 4];
  __shared__ float Bs[BK][BN + 4];
  int tid = threadIdx.x;
  int tx = tid & 15, ty = tid >> 4;
  int row0 = blockIdx.y * BM, col0 = blockIdx.x * BN;
  float acc[4][4] = {};

  for (int k0 = 0; k0 < K; k0 += BK) {
#pragma unroll
    for (int i = 0; i < 4; i++) {
      int idx = tid + i * 256;
      int m = idx >> 4;
      int k = idx & 15;
      As[k][m] = A[(long)(row0 + m) * K + k0 + k];
      Bs[k][m] = Bm[(long)(col0 + m) * K + k0 + k];
    }
    __syncthreads();
#pragma unroll
    for (int k = 0; k < BK; k++) {
      float a[4], b[4];
#pragma unroll
      for (int i = 0; i < 4; i++) a[i] = As[k][ty * 4 + i];
#pragma unroll
      for (int j = 0; j < 4; j++) b[j] = Bs[k][tx * 4 + j];
#pragma unroll
      for (int i = 0; i < 4; i++)
#pragma unroll
        for (int j = 0; j < 4; j++) acc[i][j] += a[i] * b[j];
    }
    __syncthreads();
  }
#pragma unroll
  for (int i = 0; i < 4; i++) {
    long off = (long)(row0 + ty * 4 + i) * N + col0 + tx * 4;
    *(float4*)(C + off) = make_float4(acc[i][0], acc[i][1], acc[i][2], acc[i][3]);
  }
}

// -------- bf16 MFMA GEMM: C(+)= A[M,K] @ B[N,K]^T, 64x64 tile -----------
// Both fragments loaded from row-major bf16 with the SAME lane->k mapping,
// so the result is invariant to the HW k-permutation. C/D layout is the
// verified col=lane&15, row=(lane>>4)*4+reg.
// EPI 0: unsafeAtomicAdd into f32 C (split-K). EPI 1: relu(acc)*relu(Xr) -> bf16 C.
// TRI 1: skip tiles strictly above the diagonal.
template <int EPI, int TRI>
__global__ __launch_bounds__(256) void k_mfma_abT(
    const u16* __restrict__ A, const u16* __restrict__ Bm, void* __restrict__ Cv,
    const u16* __restrict__ Xr, int M, int N, int K, int KS,
    long sA, long sB, long sC) {
  int bz = blockIdx.z;
  int batch = bz / KS, ks = bz - batch * KS;
  int row0 = blockIdx.y * 64, col0 = blockIdx.x * 64;
  if (TRI && col0 > row0) return;
  A += (long)batch * sA;
  Bm += (long)batch * sB;
  int kLen = K / KS, k0beg = ks * kLen;

  __shared__ __align__(16) u16 As[64 * 64];
  __shared__ __align__(16) u16 Bs[64 * 64];
  int tid = threadIdx.x;
  int w = tid >> 6, lane = tid & 63;
  int qr = (w >> 1) * 32, qc = (w & 1) * 32;
  int l15 = lane & 15, lhi = lane >> 4;

  f4acc acc[2][2];
#pragma unroll
  for (int i = 0; i < 2; i++)
#pragma unroll
    for (int j = 0; j < 2; j++)
#pragma unroll
      for (int e = 0; e < 4; e++) acc[i][j][e] = 0.f;

  for (int k0 = k0beg; k0 < k0beg + kLen; k0 += 64) {
    __syncthreads();
#pragma unroll
    for (int p = 0; p < 2; p++) {
      int idx = tid + p * 256;
      int r = idx >> 3, c8 = (idx & 7) * 8;           // 8 bf16 = 16B chunk
      uint4 av = *(const uint4*)(A + (long)(row0 + r) * K + k0 + c8);
      uint4 bv = *(const uint4*)(Bm + (long)(col0 + r) * K + k0 + c8);
      int sw = (c8 * 2) ^ ((r & 7) << 4);             // XOR bank swizzle
      *(uint4*)((char*)As + r * 128 + sw) = av;
      *(uint4*)((char*)Bs + r * 128 + sw) = bv;
    }
    __syncthreads();
#pragma unroll
    for (int kk = 0; kk < 2; kk++) {
      bfrag af[2], bf[2];
      int cb = kk * 64 + lhi * 16;                    // byte col within 128B row
#pragma unroll
      for (int f = 0; f < 2; f++) {
        int ra = qr + f * 16 + l15;
        af[f] = *(const bfrag*)((const char*)As + ra * 128 + (cb ^ ((ra & 7) << 4)));
        int rb = qc + f * 16 + l15;
        bf[f] = *(const bfrag*)((const char*)Bs + rb * 128 + (cb ^ ((rb & 7) << 4)));
      }
#pragma unroll
      for (int i = 0; i < 2; i++)
#pragma unroll
        for (int j = 0; j < 2; j++)
          acc[i][j] = __builtin_amdgcn_mfma_f32_16x16x32_bf16(af[i], bf[j], acc[i][j], 0, 0, 0);
    }
  }

#pragma unroll
  for (int i = 0; i < 2; i++)
#pragma unroll
    for (int j = 0; j < 2; j++) {
      int rbase = row0 + qr + i * 16 + lhi * 4;
      int c = col0 + qc + j * 16 + l15;
#pragma unroll
      for (int e = 0; e < 4; e++) {
        long r = rbase + e;
        float v = acc[i][j][e];
        if (EPI == 0) {
          unsafeAtomicAdd((float*)Cv + (long)batch * sC + r * N + c, v);
        } else {
          float xv = bf2f(Xr[r * (long)N + c]);
          ((u16*)Cv)[r * (long)N + c] = f2bf(fmaxf(v, 0.f) * fmaxf(xv, 0.f));
        }
      }
    }
}

// --------------- DPP wave-64 reduction helpers (VALU, no LDS) -----------
template <int CTRL>
__device__ __forceinline__ float dpp_mov(float v) {
  return __int_as_float(
      __builtin_amdgcn_update_dpp(0, __float_as_int(v), CTRL, 0xF, 0xF, true));
}

__device__ __forceinline__ void wave_reduce_sum_max63(float& s, float& m) {
  s += dpp_mov<0x111>(s);  m = fmaxf(m, dpp_mov<0x111>(m));  // row_shr:1
  s += dpp_mov<0x112>(s);  m = fmaxf(m, dpp_mov<0x112>(m));  // row_shr:2
  s += dpp_mov<0x114>(s);  m = fmaxf(m, dpp_mov<0x114>(m));  // row_shr:4
  s += dpp_mov<0x118>(s);  m = fmaxf(m, dpp_mov<0x118>(m));  // row_shr:8
  s += dpp_mov<0x142>(s);  m = fmaxf(m, dpp_mov<0x142>(m));  // row_bcast:15
  s += dpp_mov<0x143>(s);  m = fmaxf(m, dpp_mov<0x143>(m));  // row_bcast:31
}

__device__ __forceinline__ float wave_sum63(float s) {
  s += dpp_mov<0x111>(s);
  s += dpp_mov<0x112>(s);
  s += dpp_mov<0x114>(s);
  s += dpp_mov<0x118>(s);
  s += dpp_mov<0x142>(s);
  s += dpp_mov<0x143>(s);
  return s;
}

// ---------------- sequential x-scan: one block (4 waves) per batch ------
// Round-5 proven structure (86.6 us). Output packed to bf16 (halves write
// traffic and feeds the MFMA GEMMs directly). Plain C++ loads/stores only.
__global__ __launch_bounds__(256) void k_scan(const float* __restrict__ P,
                                              u16* __restrict__ Xb) {
  int b = blockIdx.x;
  int tid = threadIdx.x;
  int wave = tid >> 6;
  int lane = tid & 63;
  __shared__ float red[2][4][2];  // [step parity][wave][{sum,max}]

  const float4* Pv = (const float4*)(P + (long)b * T_SEQ * N_DIM);
  u16* Xrow = Xb + (long)b * T_SEQ * N_DIM;
  const int ROWQ = N_DIM / 4;  // 512 float4 per row; 256 threads x 2 each
  const long o0 = (long)tid * 2, o1 = o0 + 1;

  float x[8];
#pragma unroll
  for (int j = 0; j < 8; j++) x[j] = 0.f;

  auto rowOff = [&](int t) { return (long)(t < T_SEQ ? t : T_SEQ - 1) * ROWQ; };

  auto step = [&](const float4& v0, const float4& v1, int t) {
    float z[8];
    z[0] = 0.97f * x[0] + v0.x;
    z[1] = 0.97f * x[1] + v0.y;
    z[2] = 0.97f * x[2] + v0.z;
    z[3] = 0.97f * x[3] + v0.w;
    z[4] = 0.97f * x[4] + v1.x;
    z[5] = 0.97f * x[5] + v1.y;
    z[6] = 0.97f * x[6] + v1.z;
    z[7] = 0.97f * x[7] + v1.w;
    float s0 = fabsf(z[0]) + fabsf(z[4]);
    float s1 = fabsf(z[1]) + fabsf(z[5]);
    float s2 = fabsf(z[2]) + fabsf(z[6]);
    float s3 = fabsf(z[3]) + fabsf(z[7]);
    float m0 = fmaxf(z[0], z[4]);
    float m1 = fmaxf(z[1], z[5]);
    float m2 = fmaxf(z[2], z[6]);
    float m3 = fmaxf(z[3], z[7]);
    float s = (s0 + s1) + (s2 + s3);
    float m = fmaxf(fmaxf(m0, m1), fmaxf(m2, m3));
    wave_reduce_sum_max63(s, m);
    int par = t & 1;
    if (lane == 63) {
      red[par][wave][0] = s;
      red[par][wave][1] = m;
    }
    __syncthreads();
    float S = (red[par][0][0] + red[par][1][0]) + (red[par][2][0] + red[par][3][0]);
    float M = fmaxf(fmaxf(red[par][0][1], red[par][1][1]),
                    fmaxf(red[par][2][1], red[par][3][1]));
    float inv = 1.f / (S + 1e-6f);
    float thr = 0.02f * M;  // threshold in un-normalized space (scale-invariant)
#pragma unroll
    for (int j = 0; j < 8; j++) x[j] = (z[j] > thr) ? z[j] * inv : 0.f;
    uint4 pk;
    pk.x = (u32)f2bf(x[0]) | ((u32)f2bf(x[1]) << 16);
    pk.y = (u32)f2bf(x[2]) | ((u32)f2bf(x[3]) << 16);
    pk.z = (u32)f2bf(x[4]) | ((u32)f2bf(x[5]) << 16);
    pk.w = (u32)f2bf(x[6]) | ((u32)f2bf(x[7]) << 16);
    *(uint4*)(Xrow + (long)t * N_DIM + tid * 8) = pk;
  };

  // rotating 4-buffer register pipeline (compiler-scheduled)
  float4 A0 = Pv[rowOff(0) + o0], A1 = Pv[rowOff(0) + o1];
  float4 B0 = Pv[rowOff(1) + o0], B1 = Pv[rowOff(1) + o1];
  float4 C0 = Pv[rowOff(2) + o0], C1 = Pv[rowOff(2) + o1];
  float4 D0, D1;

  for (int t = 0; t < T_SEQ; t += 4) {
    D0 = Pv[rowOff(t + 3) + o0];
    D1 = Pv[rowOff(t + 3) + o1];
    step(A0, A1, t);
    A0 = Pv[rowOff(t + 4) + o0];
    A1 = Pv[rowOff(t + 4) + o1];
    step(B0, B1, t + 1);
    B0 = Pv[rowOff(t + 5) + o0];
    B1 = Pv[rowOff(t + 5) + o1];
    step(C0, C1, t + 2);
    C0 = Pv[rowOff(t + 6) + o0];
    C1 = Pv[rowOff(t + 6) + o1];
    step(D0, D1, t + 3);
  }
}

// -- a_star[b,t,d] = sum_{s<t} 0.97^(t-s)*S[b,t,s]*Vp[b,s,d], then LN ----
// Writes bf16 (feeds the bf16 MFMA Yt GEMM).
__global__ __launch_bounds__(128) void k_astar_ln(const float* __restrict__ S,
                                                  const float* __restrict__ Vp,
                                                  u16* __restrict__ LnAb) {
  int bx = blockIdx.x;
  int b = bx >> 8, t = bx & 255;
  int d = threadIdx.x;
  int wave = d >> 6, lane = d & 63;
  __shared__ float redS[2], redV[2];
  const float* Sb = S + ((long)b * T_SEQ + t) * T_SEQ;
  const float* Vb = Vp + (long)b * T_SEQ * D_DIM;
  float acc = 0.f;
  float w = 1.f;
  for (int s = t - 1; s >= 0; s--) {
    w *= 0.97f;
    acc += w * Sb[s] * Vb[(long)s * D_DIM + d];
  }
  float s1 = wave_sum63(acc);
  if (lane == 63) redS[wave] = s1;
  __syncthreads();
  float mean = (redS[0] + redS[1]) * (1.f / 128.f);
  float dv = acc - mean;
  float v = wave_sum63(dv * dv);
  if (lane == 63) redV[wave] = v;
  __syncthreads();
  float sd = sqrtf((redV[0] + redV[1]) * (1.f / 127.f));
  LnAb[((long)b * T_SEQ + t) * D_DIM + d] = f2bf(dv / (sd + 1e-6f));
}

// ------------- row layernorm over D=128 (torch ddof=1 semantics) --------
__global__ __launch_bounds__(64) void k_ln(const float* __restrict__ In,
                                           float* __restrict__ Out) {
  long base = (long)blockIdx.x * D_DIM;
  int lane = threadIdx.x;
  float a = In[base + lane];
  float b = In[base + lane + 64];
  float s = a + b;
#pragma unroll
  for (int off = 32; off >= 1; off >>= 1) s += __shfl_xor(s, off);
  float m = s * (1.f / 128.f);
  float da = a - m, db = b - m;
  float v = da * da + db * db;
#pragma unroll
  for (int off = 32; off >= 1; off >>= 1) v += __shfl_xor(v, off);
  float sd = sqrtf(v * (1.f / 127.f));
  float invs = 1.f / (sd + 1e-6f);
  Out[base + lane] = da * invs;
  Out[base + lane + 64] = db * invs;
}

extern "C" void kernel_launch(void* const* d_in, const int* in_sizes, int n_in,
                              void* d_out, int out_size, void* d_ws, size_t ws_size,
                              hipStream_t stream) {
  const float* E = (const float*)d_in[0];     // [128, 2048]
  const float* Dx = (const float*)d_in[1];    // [2048, 128]
  const float* Dy = (const float*)d_in[2];    // [2048, 128]
  const float* emb = (const float*)d_in[3];   // [131072, 128]
  const int* toks = (const int*)d_in[4];      // [8, 256]
  float* out = (float*)d_out;                 // [8, 256, 128]

  char* ws = (char*)d_ws;
  const size_t MB = 1u << 20;
  float* Vp = (float*)(ws + 0 * MB);            // 1 MB    [2048,128] f32
  float* P = (float*)(ws + 1 * MB);             // 16 MB   [2048,2048] f32
  u16* Ytb = (u16*)(ws + 1 * MB);               // 8 MB    reuse (P dead after scan)
  u16* Xb = (u16*)(ws + 17 * MB);               // 8 MB    [2048,2048] bf16
  float* S = (float*)(ws + 25 * MB);            // 2 MB    [8,256,256] f32  } contiguous
  float* U = (float*)(ws + 27 * MB);            // 1 MB    [2048,128] f32   } zero range
  u16* LnAb = (u16*)(ws + 28 * MB);             // 0.5 MB  [2048,128] bf16
  u16* Dyb = (u16*)(ws + 29 * MB);              // 0.5 MB
  u16* Eb = (u16*)(ws + 30 * MB);               // 0.5 MB

  const int R = B_BATCH * T_SEQ;  // 2048

  k_gather<<<R, D_DIM, 0, stream>>>(emb, toks, Vp);
  k_cast<<<256, 256, 0, stream>>>(Dy, Dyb, N_DIM * D_DIM);
  k_cast<<<256, 256, 0, stream>>>(E, Eb, N_DIM * D_DIM);
  // P = Vp @ Dx^T (f32 — feeds the threshold-sensitive scan)
  k_gemm_abT<<<dim3(N_DIM / 64, R / 64, 1), 256, 0, stream>>>(
      Vp, Dx, P, R, N_DIM, D_DIM);
  // sequential x-scan -> bf16 X
  k_scan<<<B_BATCH, 256, 0, stream>>>(P, Xb);
  // zero split-K accumulators S+U (3 MB contiguous)
  k_zero<<<768, 256, 0, stream>>>(S, 3L * MB / 16);
  // S = X @ X^T per batch, bf16 MFMA, lower-tri tiles, split-K x4
  k_mfma_abT<0, 1><<<dim3(4, 4, B_BATCH * 4), 256, 0, stream>>>(
      Xb, Xb, S, nullptr, T_SEQ, T_SEQ, N_DIM, 4,
      (long)T_SEQ * N_DIM, (long)T_SEQ * N_DIM, (long)T_SEQ * T_SEQ);
  // a_star = (decay-masked S) @ Vp, fused LN, bf16 out
  k_astar_ln<<<R, D_DIM, 0, stream>>>(S, Vp, LnAb);
  // Yt = relu(LnAb @ Dyb^T) * relu(Xb) -> bf16, MFMA
  k_mfma_abT<1, 0><<<dim3(N_DIM / 64, R / 64, 1), 256, 0, stream>>>(
      LnAb, Dyb, Ytb, Xb, R, N_DIM, D_DIM, 1, 0, 0, 0);
  // U = Ytb @ Eb^T, MFMA split-K x8 (f32 atomics)
  k_mfma_abT<0, 0><<<dim3(D_DIM / 64, R / 64, 8), 256, 0, stream>>>(
      Ytb, Eb, U, nullptr, R, D_DIM, N_DIM, 8, 0, 0, 0);
  k_ln<<<R, 64, 0, stream>>>(U, out);
}